// Round 12
// baseline (401.261 us; speedup 1.0000x reference)
//
#include <hip/hip_runtime.h>
#include <hip/hip_bf16.h>
#include <math.h>

#define BB 16
#define TT 512
#define NN 128
#define PREDN 256
#define DMC 32
#define LL 768
constexpr float EPSF = 1e-5f;
using bf16 = __hip_bfloat16;

// ---------------- K_pre: stats partials + weight fold + conv weight transposes ----------------
__global__ void k_pre(const float* __restrict__ bx, const float* __restrict__ v0,
                      const float* __restrict__ v1, const float* __restrict__ w1c,
                      const float* __restrict__ w2c, float* __restrict__ sp,
                      float* __restrict__ s2p, float* __restrict__ vwsT,
                      float* __restrict__ wT1, float* __restrict__ wT2){
  int blk = blockIdx.x;
  if(blk < 64){
    int b = blk >> 2, tq = blk & 3, n = threadIdx.x;
    const float* p = bx + (size_t)b*TT*NN + (size_t)tq*128*NN + n;
    float s = 0.f, s2 = 0.f;
    for(int t=0;t<128;t++){ float v = p[(size_t)t*NN]; s += v; s2 += v*v; }
    sp[tq*2048 + b*NN + n] = s;
    s2p[tq*2048 + b*NN + n] = s2;
  } else if(blk == 64){
    for(int i=threadIdx.x; i<9*DMC; i+=blockDim.x){
      int tap = i/DMC, c = i%DMC;
      float wv = 0.5f*v1[c*9 + tap];
      if(tap == 4) wv += 0.5f*v0[c];
      vwsT[i] = wv;
    }
  } else if(blk <= 192){
    int o = blk - 65;
    for(int k=threadIdx.x; k<1536; k+=blockDim.x)
      wT1[(size_t)k*NN + o] = w1c[(size_t)o*1536 + k];
  } else {
    int o = blk - 193;
    for(int k=threadIdx.x; k<512; k+=blockDim.x)
      wT2[(size_t)k*NN + o] = w2c[(size_t)o*512 + k];
  }
}

// ---------------- K1: GEMM1, 32x64 tile (2x4/thread), fused norm + dual store ----------------
__global__ __launch_bounds__(256) void k_gemm1(const float* __restrict__ bx, const float* __restrict__ lew,
    const float* __restrict__ leb, const float* __restrict__ sp, const float* __restrict__ s2p,
    float* __restrict__ x, float* __restrict__ a0){
  __shared__ alignas(16) float As[16][36];
  __shared__ alignas(16) float Bs[16][68];
  int tid = threadIdx.x;
  int row0 = blockIdx.x*32, l0 = blockIdx.y*64;
  int b = row0 >> 7, n0 = row0 & 127;
  float acc[2][4] = {};
  int lk = tid & 15, lr = tid >> 4;
  int tr = tid & 15, tc = tid >> 4;
  // per-loader-row normalization constants (rows lr and lr+16)
  float mu0, rs0, mu1, rs1;
  {
    int r0 = row0 + lr, r1 = row0 + lr + 16;
    float s0 = 0.f, q0 = 0.f, s1 = 0.f, q1 = 0.f;
    #pragma unroll
    for(int tq=0;tq<4;tq++){
      s0 += sp[tq*2048 + r0]; q0 += s2p[tq*2048 + r0];
      s1 += sp[tq*2048 + r1]; q1 += s2p[tq*2048 + r1];
    }
    mu0 = s0*(1.f/512.f); rs0 = 1.f/sqrtf(fmaxf(q0*(1.f/512.f) - mu0*mu0, 0.f) + EPSF);
    mu1 = s1*(1.f/512.f); rs1 = 1.f/sqrtf(fmaxf(q1*(1.f/512.f) - mu1*mu1, 0.f) + EPSF);
  }
  for(int k0=0;k0<TT;k0+=16){
    const float* bxk = bx + ((size_t)b*TT + k0 + lk)*NN + n0;
    As[lk][lr]      = (bxk[lr]      - mu0)*rs0;
    As[lk][lr + 16] = (bxk[lr + 16] - mu1)*rs1;
    #pragma unroll
    for(int q=0;q<4;q++){
      int c = lr + 16*q;
      Bs[lk][c] = lew[(size_t)(l0+c)*TT + k0 + lk];
    }
    __syncthreads();
    #pragma unroll
    for(int kk=0;kk<16;kk++){
      float2 av = *(const float2*)&As[kk][2*tr];
      float4 bv = *(const float4*)&Bs[kk][4*tc];
      float aa[2] = {av.x, av.y};
      float bb[4] = {bv.x, bv.y, bv.z, bv.w};
      #pragma unroll
      for(int i=0;i<2;i++)
        #pragma unroll
        for(int j=0;j<4;j++) acc[i][j] = fmaf(aa[i], bb[j], acc[i][j]);
    }
    __syncthreads();
  }
  #pragma unroll
  for(int i=0;i<2;i++){
    int row = row0 + 2*tr + i;
    int l = l0 + 4*tc;
    float4 st;
    st.x = acc[i][0] + leb[l+0];
    st.y = acc[i][1] + leb[l+1];
    st.z = acc[i][2] + leb[l+2];
    st.w = acc[i][3] + leb[l+3];
    *(float4*)&x[(size_t)row*LL + l] = st;
  }
  #pragma unroll
  for(int j=0;j<4;j++){
    int l = l0 + 4*tc + j;
    float lb = leb[l];
    float2 st;
    st.x = acc[0][j] + lb;
    st.y = acc[1][j] + lb;
    *(float2*)&a0[((size_t)b*3*LL + l)*NN + n0 + 2*tr] = st;
  }
}

// ---------------- K3: conv1 (coalesced wT, 4 j per block) ----------------
__global__ __launch_bounds__(512) void k_conv1(const float* __restrict__ x, const float* __restrict__ wT,
                                               const float* __restrict__ bias, float* __restrict__ t1){
  __shared__ alignas(16) float xs[NN*48];
  int jt = blockIdx.x, b = blockIdx.y;
  int tid = threadIdx.x;
  int o = tid & 127, jj = tid >> 7;
  for(int i=tid;i<NN*48;i+=512){
    int ci = i/48, kk = i%48;
    xs[i] = x[((size_t)b*NN + ci)*LL + jt*48 + kk];
  }
  __syncthreads();
  float a0 = 0.f, a1 = 0.f, a2 = 0.f, a3 = 0.f;
  for(int ci=0;ci<NN;ci++){
    const float* xc = xs + ci*48 + jj*12;
    const float* wc = wT + (size_t)(ci*12)*NN + o;
    #pragma unroll
    for(int kk=0;kk<12;kk+=4){
      a0 = fmaf(xc[kk+0], wc[(size_t)(kk+0)*NN], a0);
      a1 = fmaf(xc[kk+1], wc[(size_t)(kk+1)*NN], a1);
      a2 = fmaf(xc[kk+2], wc[(size_t)(kk+2)*NN], a2);
      a3 = fmaf(xc[kk+3], wc[(size_t)(kk+3)*NN], a3);
    }
  }
  int j = jt*4 + jj;
  t1[((size_t)b*NN + o)*64 + j] = (a0 + a1) + (a2 + a3) + bias[o];
}

// ---------------- K4: BN stats per channel ----------------
__global__ void k_bnstats(const float* __restrict__ t, const float* __restrict__ g, const float* __restrict__ bb,
                          int Bcnt, int Jcnt, float* __restrict__ scale, float* __restrict__ shift){
  int o = blockIdx.x;
  int tot = Bcnt*Jcnt;
  float s = 0.f, s2 = 0.f;
  for(int i=threadIdx.x; i<tot; i+=blockDim.x){
    int b = i / Jcnt, j = i % Jcnt;
    float v = t[((size_t)b*NN + o)*Jcnt + j];
    s += v; s2 += v*v;
  }
  __shared__ float rs[256], rs2[256];
  rs[threadIdx.x] = s; rs2[threadIdx.x] = s2;
  __syncthreads();
  for(int st=128; st>0; st>>=1){
    if(threadIdx.x < st){ rs[threadIdx.x] += rs[threadIdx.x+st]; rs2[threadIdx.x] += rs2[threadIdx.x+st]; }
    __syncthreads();
  }
  if(threadIdx.x == 0){
    float mu = rs[0]/tot;
    float var = fmaxf(rs2[0]/tot - mu*mu, 0.f);
    float sc = g[o] * rsqrtf(var + EPSF);
    scale[o] = sc; shift[o] = bb[o] - mu*sc;
  }
}

// ---------------- K5: BN apply + ELU + transpose ----------------
__global__ void k_bnelu_t(const float* __restrict__ t, const float* __restrict__ scale,
                          const float* __restrict__ shift, int Jcnt, float* __restrict__ tt){
  int j = blockIdx.x, b = blockIdx.y, o = threadIdx.x;
  float v = t[((size_t)b*NN + o)*Jcnt + j]*scale[o] + shift[o];
  v = v > 0.f ? v : (expf(v) - 1.f);
  tt[((size_t)b*Jcnt + j)*NN + o] = v;
}

// ---------------- K6: spline tridiagonal solve (Thomas) ----------------
template<int LK>
__global__ void k_spline_solve(const float* __restrict__ y, float* __restrict__ M){
  constexpr int m = LK-2;
  const float Kc = 6.f*(LK-1)*(LK-1);
  __shared__ float cp[m];
  __shared__ float dp[m][NN];
  int b = blockIdx.x, c = threadIdx.x;
  if(c == 0){
    float cv = 0.25f; cp[0] = cv;
    for(int i=1;i<m;i++){ cv = 1.f/(4.f - cv); cp[i] = cv; }
  }
  __syncthreads();
  const float* yb = y + (size_t)b*LK*NN + c;
  float y0 = yb[0], y1 = yb[NN];
  float dprev = 0.f;
  for(int i=0;i<m;i++){
    float y2 = yb[(size_t)(i+2)*NN];
    float r = (y2 - 2.f*y1 + y0)*Kc;
    float d = (i == 0) ? r*0.25f : (r - dprev)*cp[i];
    dp[i][c] = d; dprev = d;
    y0 = y1; y1 = y2;
  }
  float* Mb = M + (size_t)b*LK*NN + c;
  float xv = dp[m-1][c];
  Mb[(size_t)m*NN] = xv;
  for(int i=m-2;i>=0;i--){
    xv = dp[i][c] - cp[i]*xv;
    Mb[(size_t)(i+1)*NN] = xv;
  }
  Mb[0] = 0.f;
  Mb[(size_t)(LK-1)*NN] = 0.f;
}

// ---------------- K7: merged spline evaluation ----------------
__device__ __forceinline__ float spline_pt(const float* __restrict__ y, const float* __restrict__ M,
                                           int LK, int l, int b, int c){
  float hh = 1.f/(LK-1);
  float q = (float)l * (1.f/(LL-1));
  int idx = (int)floorf(q*(LK-1));
  if(idx > LK-2) idx = LK-2;
  float s = q - idx*hh;
  float u = hh - s;
  const float* yb = y + ((size_t)b*LK + idx)*NN + c;
  const float* Mb = M + ((size_t)b*LK + idx)*NN + c;
  float yi = yb[0], yi1 = yb[NN], M0 = Mb[0], M1 = Mb[NN];
  float hh6 = hh*hh/6.f;
  return (M0*u*u*u + M1*s*s*s)*(1.f/(6.f*hh))
       + (yi  - M0*hh6)*(u*(1.f/hh))
       + (yi1 - M1*hh6)*(s*(1.f/hh));
}

__global__ void k_spline_eval2(const float* __restrict__ y64, const float* __restrict__ M64,
                               const float* __restrict__ y16, const float* __restrict__ M16,
                               float* __restrict__ a){
  int l = blockIdx.x, b = blockIdx.y, ch = blockIdx.z, c = threadIdx.x;
  float val = (ch == 0) ? spline_pt(y64, M64, 64, l, b, c)
                        : spline_pt(y16, M16, 16, l, b, c);
  a[(((size_t)b*3 + 1 + ch)*LL + l)*NN + c] = val;
}

// ---------------- K8: conv2 (coalesced wT, 4 j per block) ----------------
__global__ __launch_bounds__(512) void k_conv2(const float* __restrict__ tt, const float* __restrict__ wT,
                                               const float* __restrict__ bias, float* __restrict__ t2){
  __shared__ alignas(16) float ts[16*NN];
  int jt = blockIdx.x, b = blockIdx.y;
  int tid = threadIdx.x;
  int o = tid & 127, jj = tid >> 7;
  for(int i=tid;i<16*NN;i+=512)
    ts[i] = tt[((size_t)b*64 + jt*16)*NN + i];
  __syncthreads();
  float a0 = 0.f, a1 = 0.f, a2 = 0.f, a3 = 0.f;
  for(int ci=0;ci<NN;ci++){
    const float* wc = wT + (size_t)(ci*4)*NN + o;
    const float* tc2 = ts + (jj*4)*NN + ci;
    a0 = fmaf(tc2[0*NN], wc[0*NN], a0);
    a1 = fmaf(tc2[1*NN], wc[1*NN], a1);
    a2 = fmaf(tc2[2*NN], wc[2*NN], a2);
    a3 = fmaf(tc2[3*NN], wc[3*NN], a3);
  }
  int j = jt*4 + jj;
  t2[((size_t)b*NN + o)*16 + j] = (a0 + a1) + (a2 + a3) + bias[o];
}

// ---------------- K_h1: stage-1 conv + GELU -> h1g bf16 [brel][l][n][c] ----------------
__global__ __launch_bounds__(256) void k_h1(const float* __restrict__ a, int bbase,
    const float* __restrict__ w0, const float* __restrict__ b0,
    const float* __restrict__ w1, const float* __restrict__ b1,
    bf16* __restrict__ h1g){
  constexpr int AY = 10, AX = 36;
  __shared__ alignas(16) float as[3][AY][AX];
  int tid = threadIdx.x;
  int l0 = blockIdx.x*8, n0 = blockIdx.y*32, brel = blockIdx.z, b = bbase + brel;
  const float* ab = a + (size_t)b*3*LL*NN;
  float* asf = &as[0][0][0];
  for(int i=tid;i<3*AY*AX;i+=256){
    int ch = i/(AY*AX), rem = i%(AY*AX), yy = rem/AX, xx = rem%AX;
    int gl = l0 + yy - 1, gn = n0 + xx - 1;
    float v = 0.f;
    if(xx < 34 && gl >= 0 && gl < LL && gn >= 0 && gn < NN) v = ab[((size_t)ch*LL + gl)*NN + gn];
    asf[i] = v;
  }
  int c = tid & 31, qg = tid >> 5;
  float wr[3][3][3];
  #pragma unroll
  for(int ci=0;ci<3;ci++)
    #pragma unroll
    for(int dy=0;dy<3;dy++)
      #pragma unroll
      for(int dx=0;dx<3;dx++){
        float wv = 0.5f*w1[((c*3+ci)*3+dy)*3+dx];
        if(dy==1 && dx==1) wv += 0.5f*w0[c*3+ci];
        wr[ci][dy][dx] = wv;
      }
  float br = 0.5f*(b0[c] + b1[c]);
  __syncthreads();
  for(int q=qg; q<64; q+=8){
    int yy = q >> 3, x0q = (q & 7)*4;
    float win[3][3][6];
    #pragma unroll
    for(int ci=0;ci<3;ci++)
      #pragma unroll
      for(int dy=0;dy<3;dy++){
        float4 r4 = *(const float4*)&as[ci][yy+dy][x0q];
        float2 r2 = *(const float2*)&as[ci][yy+dy][x0q+4];
        win[ci][dy][0]=r4.x; win[ci][dy][1]=r4.y; win[ci][dy][2]=r4.z;
        win[ci][dy][3]=r4.w; win[ci][dy][4]=r2.x; win[ci][dy][5]=r2.y;
      }
    #pragma unroll
    for(int p=0;p<4;p++){
      float s = br;
      #pragma unroll
      for(int ci=0;ci<3;ci++)
        #pragma unroll
        for(int dy=0;dy<3;dy++)
          #pragma unroll
          for(int dx=0;dx<3;dx++)
            s = fmaf(wr[ci][dy][dx], win[ci][dy][p+dx], s);
      float val = s*0.5f*(1.f + erff(s*0.70710678118654752f));
      h1g[(((size_t)brel*LL + l0 + yy)*NN + n0 + x0q + p)*DMC + c] = __float2bfloat16(val);
    }
  }
}

// ---------------- K_h2: stage-2 conv + residual, in-place into a0 ----------------
__device__ __forceinline__ float2 bf2f2(unsigned u){
  float2 r;
  r.x = __uint_as_float(u << 16);
  r.y = __uint_as_float(u & 0xffff0000u);
  return r;
}

__global__ __launch_bounds__(256) void k_h2(const bf16* __restrict__ h1g, int bbase,
    const float* __restrict__ vwsT, const float* __restrict__ vb0, const float* __restrict__ vb1,
    float* __restrict__ a){
  __shared__ unsigned h1s[10][34][17];
  int tid = threadIdx.x;
  int l0 = blockIdx.x*8, n0 = blockIdx.y*32, brel = blockIdx.z, b = bbase + brel;
  const unsigned* hg = (const unsigned*)h1g;
  for(int i=tid;i<340*16;i+=256){
    int px = i >> 4, cp = i & 15;
    int yy = px/34, xx = px - yy*34;
    int gl = l0 + yy - 1, gn = n0 + xx - 1;
    unsigned u = 0;
    if(gl >= 0 && gl < LL && gn >= 0 && gn < NN)
      u = hg[(((size_t)brel*LL + gl)*NN + gn)*16 + cp];
    h1s[yy][xx][cp] = u;
  }
  __syncthreads();
  int oy = tid >> 5, ox = tid & 31;
  float acc = 0.f;
  #pragma unroll
  for(int dy=0;dy<3;dy++)
    #pragma unroll
    for(int dx=0;dx<3;dx++){
      const unsigned* hp = &h1s[oy+dy][ox+dx][0];
      const float4* wt = (const float4*)(vwsT + (dy*3+dx)*DMC);
      #pragma unroll
      for(int cg=0;cg<8;cg++){
        unsigned u0 = hp[cg*2], u1 = hp[cg*2+1];
        float2 f0 = bf2f2(u0), f1 = bf2f2(u1);
        float4 wv = wt[cg];
        acc = fmaf(f0.x, wv.x, acc);
        acc = fmaf(f0.y, wv.y, acc);
        acc = fmaf(f1.x, wv.z, acc);
        acc = fmaf(f1.y, wv.w, acc);
      }
    }
  size_t idx = ((size_t)b*3*LL + l0 + oy)*NN + n0 + ox;
  a[idx] = acc + vb0[0] + vb1[0] + a[idx];
}

// ---------------- K15: GEMM2, 32x64 tile (2x4/thread) + de-normalize ----------------
__global__ __launch_bounds__(256) void k_gemm2(const float* __restrict__ a, const float* __restrict__ ldw,
    const float* __restrict__ ldb, const float* __restrict__ sp, const float* __restrict__ s2p,
    float* __restrict__ out){
  __shared__ alignas(16) float As[16][36];
  __shared__ alignas(16) float Bs[16][68];
  int tid = threadIdx.x;
  int row0 = blockIdx.x*32, p0 = blockIdx.y*64;
  int b = row0 >> 7, n0 = row0 & 127;
  float acc[2][4] = {};
  int lk = tid & 15, lr = tid >> 4;
  int tr = tid & 15, tc = tid >> 4;
  for(int k0=0;k0<LL;k0+=16){
    const float* ak2 = a + ((size_t)b*3*LL + k0 + lk)*NN + n0;
    As[lk][lr]      = ak2[lr];
    As[lk][lr + 16] = ak2[lr + 16];
    #pragma unroll
    for(int q=0;q<4;q++){
      int cc = lr + 16*q;
      Bs[lk][cc] = ldw[(size_t)(p0+cc)*LL + k0 + lk];
    }
    __syncthreads();
    #pragma unroll
    for(int kk=0;kk<16;kk++){
      float2 av = *(const float2*)&As[kk][2*tr];
      float4 bv = *(const float4*)&Bs[kk][4*tc];
      float aa[2] = {av.x, av.y};
      float bb[4] = {bv.x, bv.y, bv.z, bv.w};
      #pragma unroll
      for(int i=0;i<2;i++)
        #pragma unroll
        for(int j=0;j<4;j++) acc[i][j] = fmaf(aa[i], bb[j], acc[i][j]);
    }
    __syncthreads();
  }
  #pragma unroll
  for(int i=0;i<2;i++){
    int row = row0 + 2*tr + i;
    int bb2 = row >> 7, n = row & 127;
    float ssum = 0.f, s2sum = 0.f;
    #pragma unroll
    for(int tq=0;tq<4;tq++){ ssum += sp[tq*2048 + row]; s2sum += s2p[tq*2048 + row]; }
    float mu = ssum*(1.f/512.f);
    float var = fmaxf(s2sum*(1.f/512.f) - mu*mu, 0.f);
    float sd = sqrtf(var + EPSF);
    #pragma unroll
    for(int j=0;j<4;j++){
      int p = p0 + 4*tc + j;
      float v = (acc[i][j] + ldb[p])*sd + mu;
      out[((size_t)bb2*PREDN + p)*NN + n] = v;
    }
  }
}

extern "C" void kernel_launch(void* const* d_in, const int* in_sizes, int n_in,
                              void* d_out, int out_size, void* d_ws, size_t ws_size,
                              hipStream_t stream){
  (void)in_sizes; (void)n_in; (void)out_size; (void)ws_size;
  const float* batch_x = (const float*)d_in[0];
  const float* le_w  = (const float*)d_in[4];
  const float* le_b  = (const float*)d_in[5];
  const float* c1_w  = (const float*)d_in[6];
  const float* c1_b  = (const float*)d_in[7];
  const float* bn1_g = (const float*)d_in[8];
  const float* bn1_b = (const float*)d_in[9];
  const float* c2_w  = (const float*)d_in[10];
  const float* c2_b  = (const float*)d_in[11];
  const float* bn2_g = (const float*)d_in[12];
  const float* bn2_b = (const float*)d_in[13];
  const float* i1_w0 = (const float*)d_in[14];
  const float* i1_b0 = (const float*)d_in[15];
  const float* i1_w1 = (const float*)d_in[16];
  const float* i1_b1 = (const float*)d_in[17];
  const float* i2_w0 = (const float*)d_in[18];
  const float* i2_b0 = (const float*)d_in[19];
  const float* i2_w1 = (const float*)d_in[20];
  const float* i2_b1 = (const float*)d_in[21];
  const float* ld_w  = (const float*)d_in[22];
  const float* ld_b  = (const float*)d_in[23];
  float* out = (float*)d_out;

  float* ws   = (float*)d_ws;
  float* sp   = ws;                        // 8192
  float* s2p  = sp + 8192;                 // 8192
  float* vwsT = s2p + 8192;                // 288 (+pad)
  float* wT1  = vwsT + 320;                // 196,608
  float* wT2  = wT1 + 196608;              // 65,536
  float* x    = wT2 + 65536;               // 1,572,864
  float* a    = x + (size_t)BB*NN*LL;      // 4,718,592
  float* t1   = a + (size_t)BB*3*LL*NN;    // 131,072
  float* t1t  = t1 + (size_t)BB*NN*64;     // 131,072
  float* sc1  = t1t + (size_t)BB*64*NN;    // 128
  float* sh1  = sc1 + NN;                  // 128
  float* Msp1 = sh1 + NN;                  // 131,072
  float* t2   = Msp1 + (size_t)BB*64*NN;   // 32,768
  float* t2t  = t2 + (size_t)BB*NN*16;     // 32,768
  float* sc2  = t2t + (size_t)BB*16*NN;    // 128
  float* sh2  = sc2 + NN;                  // 128
  float* Msp2 = sh2 + NN;                  // 32,768
  bf16*  h1g  = (bf16*)(Msp2 + (size_t)BB*16*NN);  // 25.2 MB
  float* a0   = a;

  k_pre<<<321, 128, 0, stream>>>(batch_x, i2_w0, i2_w1, c1_w, c2_w, sp, s2p, vwsT, wT1, wT2);
  k_gemm1<<<dim3(64,12), 256, 0, stream>>>(batch_x, le_w, le_b, sp, s2p, x, a0);
  k_conv1<<<dim3(16,BB), 512, 0, stream>>>(x, wT1, c1_b, t1);
  k_bnstats<<<NN, 256, 0, stream>>>(t1, bn1_g, bn1_b, BB, 64, sc1, sh1);
  k_bnelu_t<<<dim3(64,BB), NN, 0, stream>>>(t1, sc1, sh1, 64, t1t);
  k_spline_solve<64><<<BB, NN, 0, stream>>>(t1t, Msp1);
  k_conv2<<<dim3(4,BB), 512, 0, stream>>>(t1t, wT2, c2_b, t2);
  k_bnstats<<<NN, 256, 0, stream>>>(t2, bn2_g, bn2_b, BB, 16, sc2, sh2);
  k_bnelu_t<<<dim3(16,BB), NN, 0, stream>>>(t2, sc2, sh2, 16, t2t);
  k_spline_solve<16><<<BB, NN, 0, stream>>>(t2t, Msp2);
  k_spline_eval2<<<dim3(LL,BB,2), NN, 0, stream>>>(t1t, Msp1, t2t, Msp2, a);
  for(int g=0; g<BB; g+=4){
    k_h1<<<dim3(96,4,4), 256, 0, stream>>>(a, g, i1_w0, i1_b0, i1_w1, i1_b1, h1g);
    k_h2<<<dim3(96,4,4), 256, 0, stream>>>(h1g, g, vwsT, i2_b0, i2_b1, a);
  }
  k_gemm2<<<dim3(64,4), 256, 0, stream>>>(a, ld_w, ld_b, sp, s2p, out);
}

// Round 13
// 389.879 us; speedup vs baseline: 1.0292x; 1.0292x over previous
//
#include <hip/hip_runtime.h>
#include <hip/hip_bf16.h>
#include <math.h>

#define BB 16
#define TT 512
#define NN 128
#define PREDN 256
#define DMC 32
#define LL 768
constexpr float EPSF = 1e-5f;
using bf16 = __hip_bfloat16;

// ---------------- K_pre: stats partials + weight fold + conv weight transposes ----------------
__global__ void k_pre(const float* __restrict__ bx, const float* __restrict__ v0,
                      const float* __restrict__ v1, const float* __restrict__ w1c,
                      const float* __restrict__ w2c, float* __restrict__ sp,
                      float* __restrict__ s2p, float* __restrict__ vwsT,
                      float* __restrict__ wT1, float* __restrict__ wT2){
  int blk = blockIdx.x;
  if(blk < 64){
    int b = blk >> 2, tq = blk & 3, n = threadIdx.x;
    const float* p = bx + (size_t)b*TT*NN + (size_t)tq*128*NN + n;
    float s = 0.f, s2 = 0.f;
    for(int t=0;t<128;t++){ float v = p[(size_t)t*NN]; s += v; s2 += v*v; }
    sp[tq*2048 + b*NN + n] = s;
    s2p[tq*2048 + b*NN + n] = s2;
  } else if(blk == 64){
    for(int i=threadIdx.x; i<9*DMC; i+=blockDim.x){
      int tap = i/DMC, c = i%DMC;
      float wv = 0.5f*v1[c*9 + tap];
      if(tap == 4) wv += 0.5f*v0[c];
      vwsT[i] = wv;
    }
  } else if(blk <= 192){
    int o = blk - 65;
    for(int k=threadIdx.x; k<1536; k+=blockDim.x)
      wT1[(size_t)k*NN + o] = w1c[(size_t)o*1536 + k];
  } else {
    int o = blk - 193;
    for(int k=threadIdx.x; k<512; k+=blockDim.x)
      wT2[(size_t)k*NN + o] = w2c[(size_t)o*512 + k];
  }
}

// ---------------- K1: GEMM1, 32x64 tile, register-pipelined, fused norm + dual store ----------------
__global__ __launch_bounds__(256) void k_gemm1(const float* __restrict__ bx, const float* __restrict__ lew,
    const float* __restrict__ leb, const float* __restrict__ sp, const float* __restrict__ s2p,
    float* __restrict__ x, float* __restrict__ a0){
  __shared__ alignas(16) float As[16][36];
  __shared__ alignas(16) float Bs[16][68];
  int tid = threadIdx.x;
  int row0 = blockIdx.x*32, l0 = blockIdx.y*64;
  int b = row0 >> 7, n0 = row0 & 127;
  float acc[2][4] = {};
  int lk = tid & 15, lr = tid >> 4;
  int tr = tid & 15, tc = tid >> 4;
  float mu0, rs0, mu1, rs1;
  {
    int r0 = row0 + lr, r1 = row0 + lr + 16;
    float s0 = 0.f, q0 = 0.f, s1 = 0.f, q1 = 0.f;
    #pragma unroll
    for(int tq=0;tq<4;tq++){
      s0 += sp[tq*2048 + r0]; q0 += s2p[tq*2048 + r0];
      s1 += sp[tq*2048 + r1]; q1 += s2p[tq*2048 + r1];
    }
    mu0 = s0*(1.f/512.f); rs0 = 1.f/sqrtf(fmaxf(q0*(1.f/512.f) - mu0*mu0, 0.f) + EPSF);
    mu1 = s1*(1.f/512.f); rs1 = 1.f/sqrtf(fmaxf(q1*(1.f/512.f) - mu1*mu1, 0.f) + EPSF);
  }
  float ra0, ra1, rb[4];
  {
    const float* bxk = bx + ((size_t)b*TT + lk)*NN + n0;
    ra0 = (bxk[lr] - mu0)*rs0;
    ra1 = (bxk[lr + 16] - mu1)*rs1;
    #pragma unroll
    for(int q=0;q<4;q++) rb[q] = lew[(size_t)(l0 + lr + 16*q)*TT + lk];
  }
  for(int k0=0;k0<TT;k0+=16){
    As[lk][lr]      = ra0;
    As[lk][lr + 16] = ra1;
    #pragma unroll
    for(int q=0;q<4;q++) Bs[lk][lr + 16*q] = rb[q];
    __syncthreads();
    if(k0 + 16 < TT){
      const float* bxk = bx + ((size_t)b*TT + k0 + 16 + lk)*NN + n0;
      ra0 = (bxk[lr] - mu0)*rs0;
      ra1 = (bxk[lr + 16] - mu1)*rs1;
      #pragma unroll
      for(int q=0;q<4;q++) rb[q] = lew[(size_t)(l0 + lr + 16*q)*TT + k0 + 16 + lk];
    }
    #pragma unroll
    for(int kk=0;kk<16;kk++){
      float2 av = *(const float2*)&As[kk][2*tr];
      float4 bv = *(const float4*)&Bs[kk][4*tc];
      float aa[2] = {av.x, av.y};
      float bb[4] = {bv.x, bv.y, bv.z, bv.w};
      #pragma unroll
      for(int i=0;i<2;i++)
        #pragma unroll
        for(int j=0;j<4;j++) acc[i][j] = fmaf(aa[i], bb[j], acc[i][j]);
    }
    __syncthreads();
  }
  #pragma unroll
  for(int i=0;i<2;i++){
    int row = row0 + 2*tr + i;
    int l = l0 + 4*tc;
    float4 st;
    st.x = acc[i][0] + leb[l+0];
    st.y = acc[i][1] + leb[l+1];
    st.z = acc[i][2] + leb[l+2];
    st.w = acc[i][3] + leb[l+3];
    *(float4*)&x[(size_t)row*LL + l] = st;
  }
  #pragma unroll
  for(int j=0;j<4;j++){
    int l = l0 + 4*tc + j;
    float lb = leb[l];
    float2 st;
    st.x = acc[0][j] + lb;
    st.y = acc[1][j] + lb;
    *(float2*)&a0[((size_t)b*3*LL + l)*NN + n0 + 2*tr] = st;
  }
}

// ---------------- K3: conv1 (coalesced wT, 4 j per block) ----------------
__global__ __launch_bounds__(512) void k_conv1(const float* __restrict__ x, const float* __restrict__ wT,
                                               const float* __restrict__ bias, float* __restrict__ t1){
  __shared__ alignas(16) float xs[NN*48];
  int jt = blockIdx.x, b = blockIdx.y;
  int tid = threadIdx.x;
  int o = tid & 127, jj = tid >> 7;
  for(int i=tid;i<NN*48;i+=512){
    int ci = i/48, kk = i%48;
    xs[i] = x[((size_t)b*NN + ci)*LL + jt*48 + kk];
  }
  __syncthreads();
  float a0 = 0.f, a1 = 0.f, a2 = 0.f, a3 = 0.f;
  for(int ci=0;ci<NN;ci++){
    const float* xc = xs + ci*48 + jj*12;
    const float* wc = wT + (size_t)(ci*12)*NN + o;
    #pragma unroll
    for(int kk=0;kk<12;kk+=4){
      a0 = fmaf(xc[kk+0], wc[(size_t)(kk+0)*NN], a0);
      a1 = fmaf(xc[kk+1], wc[(size_t)(kk+1)*NN], a1);
      a2 = fmaf(xc[kk+2], wc[(size_t)(kk+2)*NN], a2);
      a3 = fmaf(xc[kk+3], wc[(size_t)(kk+3)*NN], a3);
    }
  }
  int j = jt*4 + jj;
  t1[((size_t)b*NN + o)*64 + j] = (a0 + a1) + (a2 + a3) + bias[o];
}

// ---------------- K4: BN stats per channel ----------------
__global__ void k_bnstats(const float* __restrict__ t, const float* __restrict__ g, const float* __restrict__ bb,
                          int Bcnt, int Jcnt, float* __restrict__ scale, float* __restrict__ shift){
  int o = blockIdx.x;
  int tot = Bcnt*Jcnt;
  float s = 0.f, s2 = 0.f;
  for(int i=threadIdx.x; i<tot; i+=blockDim.x){
    int b = i / Jcnt, j = i % Jcnt;
    float v = t[((size_t)b*NN + o)*Jcnt + j];
    s += v; s2 += v*v;
  }
  __shared__ float rs[256], rs2[256];
  rs[threadIdx.x] = s; rs2[threadIdx.x] = s2;
  __syncthreads();
  for(int st=128; st>0; st>>=1){
    if(threadIdx.x < st){ rs[threadIdx.x] += rs[threadIdx.x+st]; rs2[threadIdx.x] += rs2[threadIdx.x+st]; }
    __syncthreads();
  }
  if(threadIdx.x == 0){
    float mu = rs[0]/tot;
    float var = fmaxf(rs2[0]/tot - mu*mu, 0.f);
    float sc = g[o] * rsqrtf(var + EPSF);
    scale[o] = sc; shift[o] = bb[o] - mu*sc;
  }
}

// ---------------- K5: BN apply + ELU + transpose ----------------
__global__ void k_bnelu_t(const float* __restrict__ t, const float* __restrict__ scale,
                          const float* __restrict__ shift, int Jcnt, float* __restrict__ tt){
  int j = blockIdx.x, b = blockIdx.y, o = threadIdx.x;
  float v = t[((size_t)b*NN + o)*Jcnt + j]*scale[o] + shift[o];
  v = v > 0.f ? v : (expf(v) - 1.f);
  tt[((size_t)b*Jcnt + j)*NN + o] = v;
}

// ---------------- K6: spline tridiagonal solve (Thomas) ----------------
template<int LK>
__global__ void k_spline_solve(const float* __restrict__ y, float* __restrict__ M){
  constexpr int m = LK-2;
  const float Kc = 6.f*(LK-1)*(LK-1);
  __shared__ float cp[m];
  __shared__ float dp[m][NN];
  int b = blockIdx.x, c = threadIdx.x;
  if(c == 0){
    float cv = 0.25f; cp[0] = cv;
    for(int i=1;i<m;i++){ cv = 1.f/(4.f - cv); cp[i] = cv; }
  }
  __syncthreads();
  const float* yb = y + (size_t)b*LK*NN + c;
  float y0 = yb[0], y1 = yb[NN];
  float dprev = 0.f;
  for(int i=0;i<m;i++){
    float y2 = yb[(size_t)(i+2)*NN];
    float r = (y2 - 2.f*y1 + y0)*Kc;
    float d = (i == 0) ? r*0.25f : (r - dprev)*cp[i];
    dp[i][c] = d; dprev = d;
    y0 = y1; y1 = y2;
  }
  float* Mb = M + (size_t)b*LK*NN + c;
  float xv = dp[m-1][c];
  Mb[(size_t)m*NN] = xv;
  for(int i=m-2;i>=0;i--){
    xv = dp[i][c] - cp[i]*xv;
    Mb[(size_t)(i+1)*NN] = xv;
  }
  Mb[0] = 0.f;
  Mb[(size_t)(LK-1)*NN] = 0.f;
}

// ---------------- K7: merged spline evaluation ----------------
__device__ __forceinline__ float spline_pt(const float* __restrict__ y, const float* __restrict__ M,
                                           int LK, int l, int b, int c){
  float hh = 1.f/(LK-1);
  float q = (float)l * (1.f/(LL-1));
  int idx = (int)floorf(q*(LK-1));
  if(idx > LK-2) idx = LK-2;
  float s = q - idx*hh;
  float u = hh - s;
  const float* yb = y + ((size_t)b*LK + idx)*NN + c;
  const float* Mb = M + ((size_t)b*LK + idx)*NN + c;
  float yi = yb[0], yi1 = yb[NN], M0 = Mb[0], M1 = Mb[NN];
  float hh6 = hh*hh/6.f;
  return (M0*u*u*u + M1*s*s*s)*(1.f/(6.f*hh))
       + (yi  - M0*hh6)*(u*(1.f/hh))
       + (yi1 - M1*hh6)*(s*(1.f/hh));
}

__global__ void k_spline_eval2(const float* __restrict__ y64, const float* __restrict__ M64,
                               const float* __restrict__ y16, const float* __restrict__ M16,
                               float* __restrict__ a){
  int l = blockIdx.x, b = blockIdx.y, ch = blockIdx.z, c = threadIdx.x;
  float val = (ch == 0) ? spline_pt(y64, M64, 64, l, b, c)
                        : spline_pt(y16, M16, 16, l, b, c);
  a[(((size_t)b*3 + 1 + ch)*LL + l)*NN + c] = val;
}

// ---------------- K8: conv2 (coalesced wT, 4 j per block) ----------------
__global__ __launch_bounds__(512) void k_conv2(const float* __restrict__ tt, const float* __restrict__ wT,
                                               const float* __restrict__ bias, float* __restrict__ t2){
  __shared__ alignas(16) float ts[16*NN];
  int jt = blockIdx.x, b = blockIdx.y;
  int tid = threadIdx.x;
  int o = tid & 127, jj = tid >> 7;
  for(int i=tid;i<16*NN;i+=512)
    ts[i] = tt[((size_t)b*64 + jt*16)*NN + i];
  __syncthreads();
  float a0 = 0.f, a1 = 0.f, a2 = 0.f, a3 = 0.f;
  for(int ci=0;ci<NN;ci++){
    const float* wc = wT + (size_t)(ci*4)*NN + o;
    const float* tc2 = ts + (jj*4)*NN + ci;
    a0 = fmaf(tc2[0*NN], wc[0*NN], a0);
    a1 = fmaf(tc2[1*NN], wc[1*NN], a1);
    a2 = fmaf(tc2[2*NN], wc[2*NN], a2);
    a3 = fmaf(tc2[3*NN], wc[3*NN], a3);
  }
  int j = jt*4 + jj;
  t2[((size_t)b*NN + o)*16 + j] = (a0 + a1) + (a2 + a3) + bias[o];
}

// ---------------- K_h1: stage-1 conv + GELU -> h1g bf16 [brel][l][n][c] ----------------
__global__ __launch_bounds__(256) void k_h1(const float* __restrict__ a, int bbase,
    const float* __restrict__ w0, const float* __restrict__ b0,
    const float* __restrict__ w1, const float* __restrict__ b1,
    bf16* __restrict__ h1g){
  constexpr int AY = 10, AX = 36;
  __shared__ alignas(16) float as[3][AY][AX];
  int tid = threadIdx.x;
  int l0 = blockIdx.x*8, n0 = blockIdx.y*32, brel = blockIdx.z, b = bbase + brel;
  const float* ab = a + (size_t)b*3*LL*NN;
  float* asf = &as[0][0][0];
  for(int i=tid;i<3*AY*AX;i+=256){
    int ch = i/(AY*AX), rem = i%(AY*AX), yy = rem/AX, xx = rem%AX;
    int gl = l0 + yy - 1, gn = n0 + xx - 1;
    float v = 0.f;
    if(xx < 34 && gl >= 0 && gl < LL && gn >= 0 && gn < NN) v = ab[((size_t)ch*LL + gl)*NN + gn];
    asf[i] = v;
  }
  int c = tid & 31, qg = tid >> 5;
  float wr[3][3][3];
  #pragma unroll
  for(int ci=0;ci<3;ci++)
    #pragma unroll
    for(int dy=0;dy<3;dy++)
      #pragma unroll
      for(int dx=0;dx<3;dx++){
        float wv = 0.5f*w1[((c*3+ci)*3+dy)*3+dx];
        if(dy==1 && dx==1) wv += 0.5f*w0[c*3+ci];
        wr[ci][dy][dx] = wv;
      }
  float br = 0.5f*(b0[c] + b1[c]);
  __syncthreads();
  for(int q=qg; q<64; q+=8){
    int yy = q >> 3, x0q = (q & 7)*4;
    float win[3][3][6];
    #pragma unroll
    for(int ci=0;ci<3;ci++)
      #pragma unroll
      for(int dy=0;dy<3;dy++){
        float4 r4 = *(const float4*)&as[ci][yy+dy][x0q];
        float2 r2 = *(const float2*)&as[ci][yy+dy][x0q+4];
        win[ci][dy][0]=r4.x; win[ci][dy][1]=r4.y; win[ci][dy][2]=r4.z;
        win[ci][dy][3]=r4.w; win[ci][dy][4]=r2.x; win[ci][dy][5]=r2.y;
      }
    #pragma unroll
    for(int p=0;p<4;p++){
      float s = br;
      #pragma unroll
      for(int ci=0;ci<3;ci++)
        #pragma unroll
        for(int dy=0;dy<3;dy++)
          #pragma unroll
          for(int dx=0;dx<3;dx++)
            s = fmaf(wr[ci][dy][dx], win[ci][dy][p+dx], s);
      float val = s*0.5f*(1.f + erff(s*0.70710678118654752f));
      h1g[(((size_t)brel*LL + l0 + yy)*NN + n0 + x0q + p)*DMC + c] = __float2bfloat16(val);
    }
  }
}

// ---------------- K_h2: stage-2 conv + residual, in-place into a0 ----------------
__device__ __forceinline__ float2 bf2f2(unsigned u){
  float2 r;
  r.x = __uint_as_float(u << 16);
  r.y = __uint_as_float(u & 0xffff0000u);
  return r;
}

__global__ __launch_bounds__(256) void k_h2(const bf16* __restrict__ h1g, int bbase,
    const float* __restrict__ vwsT, const float* __restrict__ vb0, const float* __restrict__ vb1,
    float* __restrict__ a){
  __shared__ unsigned h1s[10][34][17];
  int tid = threadIdx.x;
  int l0 = blockIdx.x*8, n0 = blockIdx.y*32, brel = blockIdx.z, b = bbase + brel;
  const unsigned* hg = (const unsigned*)h1g;
  for(int i=tid;i<340*16;i+=256){
    int px = i >> 4, cp = i & 15;
    int yy = px/34, xx = px - yy*34;
    int gl = l0 + yy - 1, gn = n0 + xx - 1;
    unsigned u = 0;
    if(gl >= 0 && gl < LL && gn >= 0 && gn < NN)
      u = hg[(((size_t)brel*LL + gl)*NN + gn)*16 + cp];
    h1s[yy][xx][cp] = u;
  }
  __syncthreads();
  int oy = tid >> 5, ox = tid & 31;
  float acc = 0.f;
  #pragma unroll
  for(int dy=0;dy<3;dy++)
    #pragma unroll
    for(int dx=0;dx<3;dx++){
      const unsigned* hp = &h1s[oy+dy][ox+dx][0];
      const float4* wt = (const float4*)(vwsT + (dy*3+dx)*DMC);
      #pragma unroll
      for(int cg=0;cg<8;cg++){
        unsigned u0 = hp[cg*2], u1 = hp[cg*2+1];
        float2 f0 = bf2f2(u0), f1 = bf2f2(u1);
        float4 wv = wt[cg];
        acc = fmaf(f0.x, wv.x, acc);
        acc = fmaf(f0.y, wv.y, acc);
        acc = fmaf(f1.x, wv.z, acc);
        acc = fmaf(f1.y, wv.w, acc);
      }
    }
  size_t idx = ((size_t)b*3*LL + l0 + oy)*NN + n0 + ox;
  a[idx] = acc + vb0[0] + vb1[0] + a[idx];
}

// ---------------- K15: GEMM2, 32x64 tile, register-pipelined + de-normalize ----------------
__global__ __launch_bounds__(256) void k_gemm2(const float* __restrict__ a, const float* __restrict__ ldw,
    const float* __restrict__ ldb, const float* __restrict__ sp, const float* __restrict__ s2p,
    float* __restrict__ out){
  __shared__ alignas(16) float As[16][36];
  __shared__ alignas(16) float Bs[16][68];
  int tid = threadIdx.x;
  int row0 = blockIdx.x*32, p0 = blockIdx.y*64;
  int b = row0 >> 7, n0 = row0 & 127;
  float acc[2][4] = {};
  int lk = tid & 15, lr = tid >> 4;
  int tr = tid & 15, tc = tid >> 4;
  float ra0, ra1, rb[4];
  {
    const float* ak2 = a + ((size_t)b*3*LL + lk)*NN + n0;
    ra0 = ak2[lr]; ra1 = ak2[lr + 16];
    #pragma unroll
    for(int q=0;q<4;q++) rb[q] = ldw[(size_t)(p0 + lr + 16*q)*LL + lk];
  }
  for(int k0=0;k0<LL;k0+=16){
    As[lk][lr]      = ra0;
    As[lk][lr + 16] = ra1;
    #pragma unroll
    for(int q=0;q<4;q++) Bs[lk][lr + 16*q] = rb[q];
    __syncthreads();
    if(k0 + 16 < LL){
      const float* ak2 = a + ((size_t)b*3*LL + k0 + 16 + lk)*NN + n0;
      ra0 = ak2[lr]; ra1 = ak2[lr + 16];
      #pragma unroll
      for(int q=0;q<4;q++) rb[q] = ldw[(size_t)(p0 + lr + 16*q)*LL + k0 + 16 + lk];
    }
    #pragma unroll
    for(int kk=0;kk<16;kk++){
      float2 av = *(const float2*)&As[kk][2*tr];
      float4 bv = *(const float4*)&Bs[kk][4*tc];
      float aa[2] = {av.x, av.y};
      float bb[4] = {bv.x, bv.y, bv.z, bv.w};
      #pragma unroll
      for(int i=0;i<2;i++)
        #pragma unroll
        for(int j=0;j<4;j++) acc[i][j] = fmaf(aa[i], bb[j], acc[i][j]);
    }
    __syncthreads();
  }
  #pragma unroll
  for(int i=0;i<2;i++){
    int row = row0 + 2*tr + i;
    int bb2 = row >> 7, n = row & 127;
    float ssum = 0.f, s2sum = 0.f;
    #pragma unroll
    for(int tq=0;tq<4;tq++){ ssum += sp[tq*2048 + row]; s2sum += s2p[tq*2048 + row]; }
    float mu = ssum*(1.f/512.f);
    float var = fmaxf(s2sum*(1.f/512.f) - mu*mu, 0.f);
    float sd = sqrtf(var + EPSF);
    #pragma unroll
    for(int j=0;j<4;j++){
      int p = p0 + 4*tc + j;
      float v = (acc[i][j] + ldb[p])*sd + mu;
      out[((size_t)bb2*PREDN + p)*NN + n] = v;
    }
  }
}

extern "C" void kernel_launch(void* const* d_in, const int* in_sizes, int n_in,
                              void* d_out, int out_size, void* d_ws, size_t ws_size,
                              hipStream_t stream){
  (void)in_sizes; (void)n_in; (void)out_size; (void)ws_size;
  const float* batch_x = (const float*)d_in[0];
  const float* le_w  = (const float*)d_in[4];
  const float* le_b  = (const float*)d_in[5];
  const float* c1_w  = (const float*)d_in[6];
  const float* c1_b  = (const float*)d_in[7];
  const float* bn1_g = (const float*)d_in[8];
  const float* bn1_b = (const float*)d_in[9];
  const float* c2_w  = (const float*)d_in[10];
  const float* c2_b  = (const float*)d_in[11];
  const float* bn2_g = (const float*)d_in[12];
  const float* bn2_b = (const float*)d_in[13];
  const float* i1_w0 = (const float*)d_in[14];
  const float* i1_b0 = (const float*)d_in[15];
  const float* i1_w1 = (const float*)d_in[16];
  const float* i1_b1 = (const float*)d_in[17];
  const float* i2_w0 = (const float*)d_in[18];
  const float* i2_b0 = (const float*)d_in[19];
  const float* i2_w1 = (const float*)d_in[20];
  const float* i2_b1 = (const float*)d_in[21];
  const float* ld_w  = (const float*)d_in[22];
  const float* ld_b  = (const float*)d_in[23];
  float* out = (float*)d_out;

  float* ws   = (float*)d_ws;
  float* sp   = ws;                        // 8192
  float* s2p  = sp + 8192;                 // 8192
  float* vwsT = s2p + 8192;                // 288 (+pad)
  float* wT1  = vwsT + 320;                // 196,608
  float* wT2  = wT1 + 196608;              // 65,536
  float* x    = wT2 + 65536;               // 1,572,864
  float* a    = x + (size_t)BB*NN*LL;      // 4,718,592
  float* t1   = a + (size_t)BB*3*LL*NN;    // 131,072
  float* t1t  = t1 + (size_t)BB*NN*64;     // 131,072
  float* sc1  = t1t + (size_t)BB*64*NN;    // 128
  float* sh1  = sc1 + NN;                  // 128
  float* Msp1 = sh1 + NN;                  // 131,072
  float* t2   = Msp1 + (size_t)BB*64*NN;   // 32,768
  float* t2t  = t2 + (size_t)BB*NN*16;     // 32,768
  float* sc2  = t2t + (size_t)BB*16*NN;    // 128
  float* sh2  = sc2 + NN;                  // 128
  float* Msp2 = sh2 + NN;                  // 32,768
  bf16*  h1g  = (bf16*)(Msp2 + (size_t)BB*16*NN);  // 25.2 MB
  float* a0   = a;

  k_pre<<<321, 128, 0, stream>>>(batch_x, i2_w0, i2_w1, c1_w, c2_w, sp, s2p, vwsT, wT1, wT2);
  k_gemm1<<<dim3(64,12), 256, 0, stream>>>(batch_x, le_w, le_b, sp, s2p, x, a0);
  k_conv1<<<dim3(16,BB), 512, 0, stream>>>(x, wT1, c1_b, t1);
  k_bnstats<<<NN, 256, 0, stream>>>(t1, bn1_g, bn1_b, BB, 64, sc1, sh1);
  k_bnelu_t<<<dim3(64,BB), NN, 0, stream>>>(t1, sc1, sh1, 64, t1t);
  k_spline_solve<64><<<BB, NN, 0, stream>>>(t1t, Msp1);
  k_conv2<<<dim3(4,BB), 512, 0, stream>>>(t1t, wT2, c2_b, t2);
  k_bnstats<<<NN, 256, 0, stream>>>(t2, bn2_g, bn2_b, BB, 16, sc2, sh2);
  k_bnelu_t<<<dim3(16,BB), NN, 0, stream>>>(t2, sc2, sh2, 16, t2t);
  k_spline_solve<16><<<BB, NN, 0, stream>>>(t2t, Msp2);
  k_spline_eval2<<<dim3(LL,BB,2), NN, 0, stream>>>(t1t, Msp1, t2t, Msp2, a);
  for(int g=0; g<BB; g+=4){
    k_h1<<<dim3(96,4,4), 256, 0, stream>>>(a, g, i1_w0, i1_b0, i1_w1, i1_b1, h1g);
    k_h2<<<dim3(96,4,4), 256, 0, stream>>>(h1g, g, vwsT, i2_b0, i2_b1, a);
  }
  k_gemm2<<<dim3(64,4), 256, 0, stream>>>(a, ld_w, ld_b, sp, s2p, out);
}

// Round 14
// 379.526 us; speedup vs baseline: 1.0573x; 1.0273x over previous
//
#include <hip/hip_runtime.h>
#include <hip/hip_bf16.h>
#include <math.h>

#define BB 16
#define TT 512
#define NN 128
#define PREDN 256
#define DMC 32
#define LL 768
constexpr float EPSF = 1e-5f;
using bf16 = __hip_bfloat16;

// ---------------- K_pre: stats partials + weight fold + conv weight transposes ----------------
__global__ void k_pre(const float* __restrict__ bx, const float* __restrict__ v0,
                      const float* __restrict__ v1, const float* __restrict__ w1c,
                      const float* __restrict__ w2c, float* __restrict__ sp,
                      float* __restrict__ s2p, float* __restrict__ vwsT,
                      float* __restrict__ wT1, float* __restrict__ wT2){
  int blk = blockIdx.x;
  if(blk < 64){
    int b = blk >> 2, tq = blk & 3, n = threadIdx.x;
    const float* p = bx + (size_t)b*TT*NN + (size_t)tq*128*NN + n;
    float s = 0.f, s2 = 0.f;
    for(int t=0;t<128;t++){ float v = p[(size_t)t*NN]; s += v; s2 += v*v; }
    sp[tq*2048 + b*NN + n] = s;
    s2p[tq*2048 + b*NN + n] = s2;
  } else if(blk == 64){
    for(int i=threadIdx.x; i<9*DMC; i+=blockDim.x){
      int tap = i/DMC, c = i%DMC;
      float wv = 0.5f*v1[c*9 + tap];
      if(tap == 4) wv += 0.5f*v0[c];
      vwsT[i] = wv;
    }
  } else if(blk <= 192){
    int o = blk - 65;
    for(int k=threadIdx.x; k<1536; k+=blockDim.x)
      wT1[(size_t)k*NN + o] = w1c[(size_t)o*1536 + k];
  } else {
    int o = blk - 193;
    for(int k=threadIdx.x; k<512; k+=blockDim.x)
      wT2[(size_t)k*NN + o] = w2c[(size_t)o*512 + k];
  }
}

// ---------------- K1: GEMM1, 64x64 tile (4x4/thread), register-pipelined, fused norm + dual store ----------------
__global__ __launch_bounds__(256) void k_gemm1(const float* __restrict__ bx, const float* __restrict__ lew,
    const float* __restrict__ leb, const float* __restrict__ sp, const float* __restrict__ s2p,
    float* __restrict__ x, float* __restrict__ a0){
  __shared__ alignas(16) float As[16][68];
  __shared__ alignas(16) float Bs[16][68];
  int tid = threadIdx.x;
  int row0 = blockIdx.x*64, l0 = blockIdx.y*64;
  int b = row0 >> 7, n0 = row0 & 127;
  float acc[4][4] = {};
  int ar = tid & 63, ak = tid >> 6;   // A loader: 64 rows x 4 k-groups
  int bk = tid & 15, bc = tid >> 4;   // B loader: 16 k x 16 col-groups
  int tr = tid & 15, tc = tid >> 4;
  float mu_a, rs_a;
  {
    int rowa = row0 + ar;
    float ssum = 0.f, s2sum = 0.f;
    #pragma unroll
    for(int tq=0;tq<4;tq++){ ssum += sp[tq*2048 + rowa]; s2sum += s2p[tq*2048 + rowa]; }
    mu_a = ssum*(1.f/512.f);
    rs_a = 1.f/sqrtf(fmaxf(s2sum*(1.f/512.f) - mu_a*mu_a, 0.f) + EPSF);
  }
  float ra[4], rb[4];
  #pragma unroll
  for(int q=0;q<4;q++){
    ra[q] = (bx[((size_t)b*TT + ak*4 + q)*NN + n0 + ar] - mu_a)*rs_a;
    rb[q] = lew[(size_t)(l0 + bc + 16*q)*TT + bk];
  }
  for(int k0=0;k0<TT;k0+=16){
    #pragma unroll
    for(int q=0;q<4;q++){
      As[ak*4 + q][ar] = ra[q];
      Bs[bk][bc + 16*q] = rb[q];
    }
    __syncthreads();
    if(k0 + 16 < TT){
      #pragma unroll
      for(int q=0;q<4;q++){
        ra[q] = (bx[((size_t)b*TT + k0 + 16 + ak*4 + q)*NN + n0 + ar] - mu_a)*rs_a;
        rb[q] = lew[(size_t)(l0 + bc + 16*q)*TT + k0 + 16 + bk];
      }
    }
    #pragma unroll
    for(int kk=0;kk<16;kk++){
      float4 av = *(const float4*)&As[kk][4*tr];
      float4 bv = *(const float4*)&Bs[kk][4*tc];
      float aa[4] = {av.x, av.y, av.z, av.w};
      float bb[4] = {bv.x, bv.y, bv.z, bv.w};
      #pragma unroll
      for(int i=0;i<4;i++)
        #pragma unroll
        for(int j=0;j<4;j++) acc[i][j] = fmaf(aa[i], bb[j], acc[i][j]);
    }
    __syncthreads();
  }
  #pragma unroll
  for(int i=0;i<4;i++){
    int row = row0 + 4*tr + i;
    int l = l0 + 4*tc;
    float4 st;
    st.x = acc[i][0] + leb[l+0];
    st.y = acc[i][1] + leb[l+1];
    st.z = acc[i][2] + leb[l+2];
    st.w = acc[i][3] + leb[l+3];
    *(float4*)&x[(size_t)row*LL + l] = st;
  }
  // transposed store: a0[b][l][n]
  #pragma unroll
  for(int j=0;j<4;j++){
    int l = l0 + 4*tc + j;
    float lb = leb[l];
    float4 st;
    st.x = acc[0][j] + lb;
    st.y = acc[1][j] + lb;
    st.z = acc[2][j] + lb;
    st.w = acc[3][j] + lb;
    *(float4*)&a0[((size_t)b*LL + l)*NN + n0 + 4*tr] = st;
  }
}

// ---------------- K3: conv1 (coalesced wT, 4 j per block) ----------------
__global__ __launch_bounds__(512) void k_conv1(const float* __restrict__ x, const float* __restrict__ wT,
                                               const float* __restrict__ bias, float* __restrict__ t1){
  __shared__ alignas(16) float xs[NN*48];
  int jt = blockIdx.x, b = blockIdx.y;
  int tid = threadIdx.x;
  int o = tid & 127, jj = tid >> 7;
  for(int i=tid;i<NN*48;i+=512){
    int ci = i/48, kk = i%48;
    xs[i] = x[((size_t)b*NN + ci)*LL + jt*48 + kk];
  }
  __syncthreads();
  float a0 = 0.f, a1 = 0.f, a2 = 0.f, a3 = 0.f;
  for(int ci=0;ci<NN;ci++){
    const float* xc = xs + ci*48 + jj*12;
    const float* wc = wT + (size_t)(ci*12)*NN + o;
    #pragma unroll
    for(int kk=0;kk<12;kk+=4){
      a0 = fmaf(xc[kk+0], wc[(size_t)(kk+0)*NN], a0);
      a1 = fmaf(xc[kk+1], wc[(size_t)(kk+1)*NN], a1);
      a2 = fmaf(xc[kk+2], wc[(size_t)(kk+2)*NN], a2);
      a3 = fmaf(xc[kk+3], wc[(size_t)(kk+3)*NN], a3);
    }
  }
  int j = jt*4 + jj;
  t1[((size_t)b*NN + o)*64 + j] = (a0 + a1) + (a2 + a3) + bias[o];
}

// ---------------- K4: BN stats per channel ----------------
__global__ void k_bnstats(const float* __restrict__ t, const float* __restrict__ g, const float* __restrict__ bb,
                          int Bcnt, int Jcnt, float* __restrict__ scale, float* __restrict__ shift){
  int o = blockIdx.x;
  int tot = Bcnt*Jcnt;
  float s = 0.f, s2 = 0.f;
  for(int i=threadIdx.x; i<tot; i+=blockDim.x){
    int b = i / Jcnt, j = i % Jcnt;
    float v = t[((size_t)b*NN + o)*Jcnt + j];
    s += v; s2 += v*v;
  }
  __shared__ float rs[256], rs2[256];
  rs[threadIdx.x] = s; rs2[threadIdx.x] = s2;
  __syncthreads();
  for(int st=128; st>0; st>>=1){
    if(threadIdx.x < st){ rs[threadIdx.x] += rs[threadIdx.x+st]; rs2[threadIdx.x] += rs2[threadIdx.x+st]; }
    __syncthreads();
  }
  if(threadIdx.x == 0){
    float mu = rs[0]/tot;
    float var = fmaxf(rs2[0]/tot - mu*mu, 0.f);
    float sc = g[o] * rsqrtf(var + EPSF);
    scale[o] = sc; shift[o] = bb[o] - mu*sc;
  }
}

// ---------------- K5: BN apply + ELU + transpose ----------------
__global__ void k_bnelu_t(const float* __restrict__ t, const float* __restrict__ scale,
                          const float* __restrict__ shift, int Jcnt, float* __restrict__ tt){
  int j = blockIdx.x, b = blockIdx.y, o = threadIdx.x;
  float v = t[((size_t)b*NN + o)*Jcnt + j]*scale[o] + shift[o];
  v = v > 0.f ? v : (expf(v) - 1.f);
  tt[((size_t)b*Jcnt + j)*NN + o] = v;
}

// ---------------- K6: spline tridiagonal solve (Thomas) ----------------
template<int LK>
__global__ void k_spline_solve(const float* __restrict__ y, float* __restrict__ M){
  constexpr int m = LK-2;
  const float Kc = 6.f*(LK-1)*(LK-1);
  __shared__ float cp[m];
  __shared__ float dp[m][NN];
  int b = blockIdx.x, c = threadIdx.x;
  if(c == 0){
    float cv = 0.25f; cp[0] = cv;
    for(int i=1;i<m;i++){ cv = 1.f/(4.f - cv); cp[i] = cv; }
  }
  __syncthreads();
  const float* yb = y + (size_t)b*LK*NN + c;
  float y0 = yb[0], y1 = yb[NN];
  float dprev = 0.f;
  for(int i=0;i<m;i++){
    float y2 = yb[(size_t)(i+2)*NN];
    float r = (y2 - 2.f*y1 + y0)*Kc;
    float d = (i == 0) ? r*0.25f : (r - dprev)*cp[i];
    dp[i][c] = d; dprev = d;
    y0 = y1; y1 = y2;
  }
  float* Mb = M + (size_t)b*LK*NN + c;
  float xv = dp[m-1][c];
  Mb[(size_t)m*NN] = xv;
  for(int i=m-2;i>=0;i--){
    xv = dp[i][c] - cp[i]*xv;
    Mb[(size_t)(i+1)*NN] = xv;
  }
  Mb[0] = 0.f;
  Mb[(size_t)(LK-1)*NN] = 0.f;
}

// ---------------- spline point evaluation (device) ----------------
__device__ __forceinline__ float spline_pt(const float* __restrict__ y, const float* __restrict__ M,
                                           int LK, int l, int b, int c){
  float hh = 1.f/(LK-1);
  float q = (float)l * (1.f/(LL-1));
  int idx = (int)floorf(q*(LK-1));
  if(idx > LK-2) idx = LK-2;
  float s = q - idx*hh;
  float u = hh - s;
  const float* yb = y + ((size_t)b*LK + idx)*NN + c;
  const float* Mb = M + ((size_t)b*LK + idx)*NN + c;
  float yi = yb[0], yi1 = yb[NN], M0 = Mb[0], M1 = Mb[NN];
  float hh6 = hh*hh/6.f;
  return (M0*u*u*u + M1*s*s*s)*(1.f/(6.f*hh))
       + (yi  - M0*hh6)*(u*(1.f/hh))
       + (yi1 - M1*hh6)*(s*(1.f/hh));
}

// ---------------- K8: conv2 (coalesced wT, 4 j per block) ----------------
__global__ __launch_bounds__(512) void k_conv2(const float* __restrict__ tt, const float* __restrict__ wT,
                                               const float* __restrict__ bias, float* __restrict__ t2){
  __shared__ alignas(16) float ts[16*NN];
  int jt = blockIdx.x, b = blockIdx.y;
  int tid = threadIdx.x;
  int o = tid & 127, jj = tid >> 7;
  for(int i=tid;i<16*NN;i+=512)
    ts[i] = tt[((size_t)b*64 + jt*16)*NN + i];
  __syncthreads();
  float a0 = 0.f, a1 = 0.f, a2 = 0.f, a3 = 0.f;
  for(int ci=0;ci<NN;ci++){
    const float* wc = wT + (size_t)(ci*4)*NN + o;
    const float* tc2 = ts + (jj*4)*NN + ci;
    a0 = fmaf(tc2[0*NN], wc[0*NN], a0);
    a1 = fmaf(tc2[1*NN], wc[1*NN], a1);
    a2 = fmaf(tc2[2*NN], wc[2*NN], a2);
    a3 = fmaf(tc2[3*NN], wc[3*NN], a3);
  }
  int j = jt*4 + jj;
  t2[((size_t)b*NN + o)*16 + j] = (a0 + a1) + (a2 + a3) + bias[o];
}

// ---------------- K_h1: stage-1 conv + GELU -> h1g bf16; spline channels computed inline ----------------
__global__ __launch_bounds__(256) void k_h1(const float* __restrict__ a0, int bbase,
    const float* __restrict__ y64, const float* __restrict__ M64,
    const float* __restrict__ y16, const float* __restrict__ M16,
    const float* __restrict__ w0, const float* __restrict__ b0,
    const float* __restrict__ w1, const float* __restrict__ b1,
    bf16* __restrict__ h1g){
  constexpr int AY = 10, AX = 36;
  __shared__ alignas(16) float as[3][AY][AX];
  int tid = threadIdx.x;
  int l0 = blockIdx.x*8, n0 = blockIdx.y*32, brel = blockIdx.z, b = bbase + brel;
  float* asf = &as[0][0][0];
  for(int i=tid;i<3*AY*AX;i+=256){
    int ch = i/(AY*AX), rem = i%(AY*AX), yy = rem/AX, xx = rem%AX;
    int gl = l0 + yy - 1, gn = n0 + xx - 1;
    float v = 0.f;
    if(xx < 34 && gl >= 0 && gl < LL && gn >= 0 && gn < NN){
      if(ch == 0)      v = a0[((size_t)b*LL + gl)*NN + gn];
      else if(ch == 1) v = spline_pt(y64, M64, 64, gl, b, gn);
      else             v = spline_pt(y16, M16, 16, gl, b, gn);
    }
    asf[i] = v;
  }
  int c = tid & 31, qg = tid >> 5;
  float wr[3][3][3];
  #pragma unroll
  for(int ci=0;ci<3;ci++)
    #pragma unroll
    for(int dy=0;dy<3;dy++)
      #pragma unroll
      for(int dx=0;dx<3;dx++){
        float wv = 0.5f*w1[((c*3+ci)*3+dy)*3+dx];
        if(dy==1 && dx==1) wv += 0.5f*w0[c*3+ci];
        wr[ci][dy][dx] = wv;
      }
  float br = 0.5f*(b0[c] + b1[c]);
  __syncthreads();
  for(int q=qg; q<64; q+=8){
    int yy = q >> 3, x0q = (q & 7)*4;
    float win[3][3][6];
    #pragma unroll
    for(int ci=0;ci<3;ci++)
      #pragma unroll
      for(int dy=0;dy<3;dy++){
        float4 r4 = *(const float4*)&as[ci][yy+dy][x0q];
        float2 r2 = *(const float2*)&as[ci][yy+dy][x0q+4];
        win[ci][dy][0]=r4.x; win[ci][dy][1]=r4.y; win[ci][dy][2]=r4.z;
        win[ci][dy][3]=r4.w; win[ci][dy][4]=r2.x; win[ci][dy][5]=r2.y;
      }
    #pragma unroll
    for(int p=0;p<4;p++){
      float s = br;
      #pragma unroll
      for(int ci=0;ci<3;ci++)
        #pragma unroll
        for(int dy=0;dy<3;dy++)
          #pragma unroll
          for(int dx=0;dx<3;dx++)
            s = fmaf(wr[ci][dy][dx], win[ci][dy][p+dx], s);
      float val = s*0.5f*(1.f + erff(s*0.70710678118654752f));
      h1g[(((size_t)brel*LL + l0 + yy)*NN + n0 + x0q + p)*DMC + c] = __float2bfloat16(val);
    }
  }
}

// ---------------- K_h2: stage-2 conv + residual, in-place into a0 ----------------
__device__ __forceinline__ float2 bf2f2(unsigned u){
  float2 r;
  r.x = __uint_as_float(u << 16);
  r.y = __uint_as_float(u & 0xffff0000u);
  return r;
}

__global__ __launch_bounds__(256) void k_h2(const bf16* __restrict__ h1g, int bbase,
    const float* __restrict__ vwsT, const float* __restrict__ vb0, const float* __restrict__ vb1,
    float* __restrict__ a0){
  __shared__ unsigned h1s[10][34][17];
  int tid = threadIdx.x;
  int l0 = blockIdx.x*8, n0 = blockIdx.y*32, brel = blockIdx.z, b = bbase + brel;
  const unsigned* hg = (const unsigned*)h1g;
  for(int i=tid;i<340*16;i+=256){
    int px = i >> 4, cp = i & 15;
    int yy = px/34, xx = px - yy*34;
    int gl = l0 + yy - 1, gn = n0 + xx - 1;
    unsigned u = 0;
    if(gl >= 0 && gl < LL && gn >= 0 && gn < NN)
      u = hg[(((size_t)brel*LL + gl)*NN + gn)*16 + cp];
    h1s[yy][xx][cp] = u;
  }
  __syncthreads();
  int oy = tid >> 5, ox = tid & 31;
  float acc = 0.f;
  #pragma unroll
  for(int dy=0;dy<3;dy++)
    #pragma unroll
    for(int dx=0;dx<3;dx++){
      const unsigned* hp = &h1s[oy+dy][ox+dx][0];
      const float4* wt = (const float4*)(vwsT + (dy*3+dx)*DMC);
      #pragma unroll
      for(int cg=0;cg<8;cg++){
        unsigned u0 = hp[cg*2], u1 = hp[cg*2+1];
        float2 f0 = bf2f2(u0), f1 = bf2f2(u1);
        float4 wv = wt[cg];
        acc = fmaf(f0.x, wv.x, acc);
        acc = fmaf(f0.y, wv.y, acc);
        acc = fmaf(f1.x, wv.z, acc);
        acc = fmaf(f1.y, wv.w, acc);
      }
    }
  size_t idx = ((size_t)b*LL + l0 + oy)*NN + n0 + ox;
  a0[idx] = acc + vb0[0] + vb1[0] + a0[idx];
}

// ---------------- K15: GEMM2, 32x64 tile, register-pipelined + de-normalize ----------------
__global__ __launch_bounds__(256) void k_gemm2(const float* __restrict__ a0, const float* __restrict__ ldw,
    const float* __restrict__ ldb, const float* __restrict__ sp, const float* __restrict__ s2p,
    float* __restrict__ out){
  __shared__ alignas(16) float As[16][36];
  __shared__ alignas(16) float Bs[16][68];
  int tid = threadIdx.x;
  int row0 = blockIdx.x*32, p0 = blockIdx.y*64;
  int b = row0 >> 7, n0 = row0 & 127;
  float acc[2][4] = {};
  int lk = tid & 15, lr = tid >> 4;
  int tr = tid & 15, tc = tid >> 4;
  float ra0, ra1, rb[4];
  {
    const float* ak2 = a0 + ((size_t)b*LL + lk)*NN + n0;
    ra0 = ak2[lr]; ra1 = ak2[lr + 16];
    #pragma unroll
    for(int q=0;q<4;q++) rb[q] = ldw[(size_t)(p0 + lr + 16*q)*LL + lk];
  }
  for(int k0=0;k0<LL;k0+=16){
    As[lk][lr]      = ra0;
    As[lk][lr + 16] = ra1;
    #pragma unroll
    for(int q=0;q<4;q++) Bs[lk][lr + 16*q] = rb[q];
    __syncthreads();
    if(k0 + 16 < LL){
      const float* ak2 = a0 + ((size_t)b*LL + k0 + 16 + lk)*NN + n0;
      ra0 = ak2[lr]; ra1 = ak2[lr + 16];
      #pragma unroll
      for(int q=0;q<4;q++) rb[q] = ldw[(size_t)(p0 + lr + 16*q)*LL + k0 + 16 + lk];
    }
    #pragma unroll
    for(int kk=0;kk<16;kk++){
      float2 av = *(const float2*)&As[kk][2*tr];
      float4 bv = *(const float4*)&Bs[kk][4*tc];
      float aa[2] = {av.x, av.y};
      float bb[4] = {bv.x, bv.y, bv.z, bv.w};
      #pragma unroll
      for(int i=0;i<2;i++)
        #pragma unroll
        for(int j=0;j<4;j++) acc[i][j] = fmaf(aa[i], bb[j], acc[i][j]);
    }
    __syncthreads();
  }
  #pragma unroll
  for(int i=0;i<2;i++){
    int row = row0 + 2*tr + i;
    int bb2 = row >> 7, n = row & 127;
    float ssum = 0.f, s2sum = 0.f;
    #pragma unroll
    for(int tq=0;tq<4;tq++){ ssum += sp[tq*2048 + row]; s2sum += s2p[tq*2048 + row]; }
    float mu = ssum*(1.f/512.f);
    float var = fmaxf(s2sum*(1.f/512.f) - mu*mu, 0.f);
    float sd = sqrtf(var + EPSF);
    #pragma unroll
    for(int j=0;j<4;j++){
      int p = p0 + 4*tc + j;
      float v = (acc[i][j] + ldb[p])*sd + mu;
      out[((size_t)bb2*PREDN + p)*NN + n] = v;
    }
  }
}

extern "C" void kernel_launch(void* const* d_in, const int* in_sizes, int n_in,
                              void* d_out, int out_size, void* d_ws, size_t ws_size,
                              hipStream_t stream){
  (void)in_sizes; (void)n_in; (void)out_size; (void)ws_size;
  const float* batch_x = (const float*)d_in[0];
  const float* le_w  = (const float*)d_in[4];
  const float* le_b  = (const float*)d_in[5];
  const float* c1_w  = (const float*)d_in[6];
  const float* c1_b  = (const float*)d_in[7];
  const float* bn1_g = (const float*)d_in[8];
  const float* bn1_b = (const float*)d_in[9];
  const float* c2_w  = (const float*)d_in[10];
  const float* c2_b  = (const float*)d_in[11];
  const float* bn2_g = (const float*)d_in[12];
  const float* bn2_b = (const float*)d_in[13];
  const float* i1_w0 = (const float*)d_in[14];
  const float* i1_b0 = (const float*)d_in[15];
  const float* i1_w1 = (const float*)d_in[16];
  const float* i1_b1 = (const float*)d_in[17];
  const float* i2_w0 = (const float*)d_in[18];
  const float* i2_b0 = (const float*)d_in[19];
  const float* i2_w1 = (const float*)d_in[20];
  const float* i2_b1 = (const float*)d_in[21];
  const float* ld_w  = (const float*)d_in[22];
  const float* ld_b  = (const float*)d_in[23];
  float* out = (float*)d_out;

  float* ws   = (float*)d_ws;
  float* sp   = ws;                        // 8192
  float* s2p  = sp + 8192;                 // 8192
  float* vwsT = s2p + 8192;                // 288 (+pad)
  float* wT1  = vwsT + 320;                // 196,608
  float* wT2  = wT1 + 196608;              // 65,536
  float* x    = wT2 + 65536;               // 1,572,864
  float* a0   = x + (size_t)BB*NN*LL;      // 1,572,864 (single channel)
  float* t1   = a0 + (size_t)BB*LL*NN;     // 131,072
  float* t1t  = t1 + (size_t)BB*NN*64;     // 131,072
  float* sc1  = t1t + (size_t)BB*64*NN;    // 128
  float* sh1  = sc1 + NN;                  // 128
  float* Msp1 = sh1 + NN;                  // 131,072
  float* t2   = Msp1 + (size_t)BB*64*NN;   // 32,768
  float* t2t  = t2 + (size_t)BB*NN*16;     // 32,768
  float* sc2  = t2t + (size_t)BB*16*NN;    // 128
  float* sh2  = sc2 + NN;                  // 128
  float* Msp2 = sh2 + NN;                  // 32,768
  bf16*  h1g  = (bf16*)(Msp2 + (size_t)BB*16*NN);  // 25.2 MB

  k_pre<<<321, 128, 0, stream>>>(batch_x, i2_w0, i2_w1, c1_w, c2_w, sp, s2p, vwsT, wT1, wT2);
  k_gemm1<<<dim3(32,12), 256, 0, stream>>>(batch_x, le_w, le_b, sp, s2p, x, a0);
  k_conv1<<<dim3(16,BB), 512, 0, stream>>>(x, wT1, c1_b, t1);
  k_bnstats<<<NN, 256, 0, stream>>>(t1, bn1_g, bn1_b, BB, 64, sc1, sh1);
  k_bnelu_t<<<dim3(64,BB), NN, 0, stream>>>(t1, sc1, sh1, 64, t1t);
  k_spline_solve<64><<<BB, NN, 0, stream>>>(t1t, Msp1);
  k_conv2<<<dim3(4,BB), 512, 0, stream>>>(t1t, wT2, c2_b, t2);
  k_bnstats<<<NN, 256, 0, stream>>>(t2, bn2_g, bn2_b, BB, 16, sc2, sh2);
  k_bnelu_t<<<dim3(16,BB), NN, 0, stream>>>(t2, sc2, sh2, 16, t2t);
  k_spline_solve<16><<<BB, NN, 0, stream>>>(t2t, Msp2);
  for(int g=0; g<BB; g+=4){
    k_h1<<<dim3(96,4,4), 256, 0, stream>>>(a0, g, t1t, Msp1, t2t, Msp2,
                                           i1_w0, i1_b0, i1_w1, i1_b1, h1g);
    k_h2<<<dim3(96,4,4), 256, 0, stream>>>(h1g, g, vwsT, i2_b0, i2_b1, a0);
  }
  k_gemm2<<<dim3(64,4), 256, 0, stream>>>(a0, ld_w, ld_b, sp, s2p, out);
}

// Round 15
// 379.223 us; speedup vs baseline: 1.0581x; 1.0008x over previous
//
#include <hip/hip_runtime.h>
#include <hip/hip_bf16.h>
#include <math.h>

#define BB 16
#define TT 512
#define NN 128
#define PREDN 256
#define DMC 32
#define LL 768
constexpr float EPSF = 1e-5f;
using bf16 = __hip_bfloat16;

// branchless tanh-approx GELU: 0.5*s*(1+tanh(0.79788456*(s+0.044715 s^3))) == s*e/(e+1),
// e = 2^(2.30211806*(s + 0.044715 s^3)).  max |err| vs exact-erf GELU ~1e-3.
__device__ __forceinline__ float gelu_fast(float s){
  float s2v = s*s;
  float e = exp2f(s*fmaf(s2v, 0.10294396f, 2.30211806f));
  return s*e*__builtin_amdgcn_rcpf(e + 1.f);
}

// ---------------- K_pre: stats partials + weight fold + conv weight transposes ----------------
__global__ void k_pre(const float* __restrict__ bx, const float* __restrict__ v0,
                      const float* __restrict__ v1, const float* __restrict__ w1c,
                      const float* __restrict__ w2c, float* __restrict__ sp,
                      float* __restrict__ s2p, float* __restrict__ vwsT,
                      float* __restrict__ wT1, float* __restrict__ wT2){
  int blk = blockIdx.x;
  if(blk < 64){
    int b = blk >> 2, tq = blk & 3, n = threadIdx.x;
    const float* p = bx + (size_t)b*TT*NN + (size_t)tq*128*NN + n;
    float s = 0.f, s2 = 0.f;
    for(int t=0;t<128;t++){ float v = p[(size_t)t*NN]; s += v; s2 += v*v; }
    sp[tq*2048 + b*NN + n] = s;
    s2p[tq*2048 + b*NN + n] = s2;
  } else if(blk == 64){
    for(int i=threadIdx.x; i<9*DMC; i+=blockDim.x){
      int tap = i/DMC, c = i%DMC;
      float wv = 0.5f*v1[c*9 + tap];
      if(tap == 4) wv += 0.5f*v0[c];
      vwsT[i] = wv;
    }
  } else if(blk <= 192){
    int o = blk - 65;
    for(int k=threadIdx.x; k<1536; k+=blockDim.x)
      wT1[(size_t)k*NN + o] = w1c[(size_t)o*1536 + k];
  } else {
    int o = blk - 193;
    for(int k=threadIdx.x; k<512; k+=blockDim.x)
      wT2[(size_t)k*NN + o] = w2c[(size_t)o*512 + k];
  }
}

// ---------------- K1: GEMM1, 64x64 tile (4x4/thread), register-pipelined, fused norm + dual store ----------------
__global__ __launch_bounds__(256) void k_gemm1(const float* __restrict__ bx, const float* __restrict__ lew,
    const float* __restrict__ leb, const float* __restrict__ sp, const float* __restrict__ s2p,
    float* __restrict__ x, float* __restrict__ a0){
  __shared__ alignas(16) float As[16][68];
  __shared__ alignas(16) float Bs[16][68];
  int tid = threadIdx.x;
  int row0 = blockIdx.x*64, l0 = blockIdx.y*64;
  int b = row0 >> 7, n0 = row0 & 127;
  float acc[4][4] = {};
  int ar = tid & 63, ak = tid >> 6;
  int bk = tid & 15, bc = tid >> 4;
  int tr = tid & 15, tc = tid >> 4;
  float mu_a, rs_a;
  {
    int rowa = row0 + ar;
    float ssum = 0.f, s2sum = 0.f;
    #pragma unroll
    for(int tq=0;tq<4;tq++){ ssum += sp[tq*2048 + rowa]; s2sum += s2p[tq*2048 + rowa]; }
    mu_a = ssum*(1.f/512.f);
    rs_a = 1.f/sqrtf(fmaxf(s2sum*(1.f/512.f) - mu_a*mu_a, 0.f) + EPSF);
  }
  float ra[4], rb[4];
  #pragma unroll
  for(int q=0;q<4;q++){
    ra[q] = (bx[((size_t)b*TT + ak*4 + q)*NN + n0 + ar] - mu_a)*rs_a;
    rb[q] = lew[(size_t)(l0 + bc + 16*q)*TT + bk];
  }
  for(int k0=0;k0<TT;k0+=16){
    #pragma unroll
    for(int q=0;q<4;q++){
      As[ak*4 + q][ar] = ra[q];
      Bs[bk][bc + 16*q] = rb[q];
    }
    __syncthreads();
    if(k0 + 16 < TT){
      #pragma unroll
      for(int q=0;q<4;q++){
        ra[q] = (bx[((size_t)b*TT + k0 + 16 + ak*4 + q)*NN + n0 + ar] - mu_a)*rs_a;
        rb[q] = lew[(size_t)(l0 + bc + 16*q)*TT + k0 + 16 + bk];
      }
    }
    #pragma unroll
    for(int kk=0;kk<16;kk++){
      float4 av = *(const float4*)&As[kk][4*tr];
      float4 bv = *(const float4*)&Bs[kk][4*tc];
      float aa[4] = {av.x, av.y, av.z, av.w};
      float bb[4] = {bv.x, bv.y, bv.z, bv.w};
      #pragma unroll
      for(int i=0;i<4;i++)
        #pragma unroll
        for(int j=0;j<4;j++) acc[i][j] = fmaf(aa[i], bb[j], acc[i][j]);
    }
    __syncthreads();
  }
  #pragma unroll
  for(int i=0;i<4;i++){
    int row = row0 + 4*tr + i;
    int l = l0 + 4*tc;
    float4 st;
    st.x = acc[i][0] + leb[l+0];
    st.y = acc[i][1] + leb[l+1];
    st.z = acc[i][2] + leb[l+2];
    st.w = acc[i][3] + leb[l+3];
    *(float4*)&x[(size_t)row*LL + l] = st;
  }
  #pragma unroll
  for(int j=0;j<4;j++){
    int l = l0 + 4*tc + j;
    float lb = leb[l];
    float4 st;
    st.x = acc[0][j] + lb;
    st.y = acc[1][j] + lb;
    st.z = acc[2][j] + lb;
    st.w = acc[3][j] + lb;
    *(float4*)&a0[((size_t)b*LL + l)*NN + n0 + 4*tr] = st;
  }
}

// ---------------- K3: conv1 (coalesced wT, 4 j per block) ----------------
__global__ __launch_bounds__(512) void k_conv1(const float* __restrict__ x, const float* __restrict__ wT,
                                               const float* __restrict__ bias, float* __restrict__ t1){
  __shared__ alignas(16) float xs[NN*48];
  int jt = blockIdx.x, b = blockIdx.y;
  int tid = threadIdx.x;
  int o = tid & 127, jj = tid >> 7;
  for(int i=tid;i<NN*48;i+=512){
    int ci = i/48, kk = i%48;
    xs[i] = x[((size_t)b*NN + ci)*LL + jt*48 + kk];
  }
  __syncthreads();
  float a0 = 0.f, a1 = 0.f, a2 = 0.f, a3 = 0.f;
  for(int ci=0;ci<NN;ci++){
    const float* xc = xs + ci*48 + jj*12;
    const float* wc = wT + (size_t)(ci*12)*NN + o;
    #pragma unroll
    for(int kk=0;kk<12;kk+=4){
      a0 = fmaf(xc[kk+0], wc[(size_t)(kk+0)*NN], a0);
      a1 = fmaf(xc[kk+1], wc[(size_t)(kk+1)*NN], a1);
      a2 = fmaf(xc[kk+2], wc[(size_t)(kk+2)*NN], a2);
      a3 = fmaf(xc[kk+3], wc[(size_t)(kk+3)*NN], a3);
    }
  }
  int j = jt*4 + jj;
  t1[((size_t)b*NN + o)*64 + j] = (a0 + a1) + (a2 + a3) + bias[o];
}

// ---------------- K4: BN stats per channel ----------------
__global__ void k_bnstats(const float* __restrict__ t, const float* __restrict__ g, const float* __restrict__ bb,
                          int Bcnt, int Jcnt, float* __restrict__ scale, float* __restrict__ shift){
  int o = blockIdx.x;
  int tot = Bcnt*Jcnt;
  float s = 0.f, s2 = 0.f;
  for(int i=threadIdx.x; i<tot; i+=blockDim.x){
    int b = i / Jcnt, j = i % Jcnt;
    float v = t[((size_t)b*NN + o)*Jcnt + j];
    s += v; s2 += v*v;
  }
  __shared__ float rs[256], rs2[256];
  rs[threadIdx.x] = s; rs2[threadIdx.x] = s2;
  __syncthreads();
  for(int st=128; st>0; st>>=1){
    if(threadIdx.x < st){ rs[threadIdx.x] += rs[threadIdx.x+st]; rs2[threadIdx.x] += rs2[threadIdx.x+st]; }
    __syncthreads();
  }
  if(threadIdx.x == 0){
    float mu = rs[0]/tot;
    float var = fmaxf(rs2[0]/tot - mu*mu, 0.f);
    float sc = g[o] * rsqrtf(var + EPSF);
    scale[o] = sc; shift[o] = bb[o] - mu*sc;
  }
}

// ---------------- K5: BN apply + ELU + transpose ----------------
__global__ void k_bnelu_t(const float* __restrict__ t, const float* __restrict__ scale,
                          const float* __restrict__ shift, int Jcnt, float* __restrict__ tt){
  int j = blockIdx.x, b = blockIdx.y, o = threadIdx.x;
  float v = t[((size_t)b*NN + o)*Jcnt + j]*scale[o] + shift[o];
  v = v > 0.f ? v : (expf(v) - 1.f);
  tt[((size_t)b*Jcnt + j)*NN + o] = v;
}

// ---------------- K6: spline tridiagonal solve (Thomas) ----------------
template<int LK>
__global__ void k_spline_solve(const float* __restrict__ y, float* __restrict__ M){
  constexpr int m = LK-2;
  const float Kc = 6.f*(LK-1)*(LK-1);
  __shared__ float cp[m];
  __shared__ float dp[m][NN];
  int b = blockIdx.x, c = threadIdx.x;
  if(c == 0){
    float cv = 0.25f; cp[0] = cv;
    for(int i=1;i<m;i++){ cv = 1.f/(4.f - cv); cp[i] = cv; }
  }
  __syncthreads();
  const float* yb = y + (size_t)b*LK*NN + c;
  float y0 = yb[0], y1 = yb[NN];
  float dprev = 0.f;
  for(int i=0;i<m;i++){
    float y2 = yb[(size_t)(i+2)*NN];
    float r = (y2 - 2.f*y1 + y0)*Kc;
    float d = (i == 0) ? r*0.25f : (r - dprev)*cp[i];
    dp[i][c] = d; dprev = d;
    y0 = y1; y1 = y2;
  }
  float* Mb = M + (size_t)b*LK*NN + c;
  float xv = dp[m-1][c];
  Mb[(size_t)m*NN] = xv;
  for(int i=m-2;i>=0;i--){
    xv = dp[i][c] - cp[i]*xv;
    Mb[(size_t)(i+1)*NN] = xv;
  }
  Mb[0] = 0.f;
  Mb[(size_t)(LK-1)*NN] = 0.f;
}

// ---------------- spline point evaluation (device) ----------------
__device__ __forceinline__ float spline_pt(const float* __restrict__ y, const float* __restrict__ M,
                                           int LK, int l, int b, int c){
  float hh = 1.f/(LK-1);
  float q = (float)l * (1.f/(LL-1));
  int idx = (int)floorf(q*(LK-1));
  if(idx > LK-2) idx = LK-2;
  float s = q - idx*hh;
  float u = hh - s;
  const float* yb = y + ((size_t)b*LK + idx)*NN + c;
  const float* Mb = M + ((size_t)b*LK + idx)*NN + c;
  float yi = yb[0], yi1 = yb[NN], M0 = Mb[0], M1 = Mb[NN];
  float hh6 = hh*hh/6.f;
  return (M0*u*u*u + M1*s*s*s)*(1.f/(6.f*hh))
       + (yi  - M0*hh6)*(u*(1.f/hh))
       + (yi1 - M1*hh6)*(s*(1.f/hh));
}

// ---------------- K8: conv2 (coalesced wT, 4 j per block) ----------------
__global__ __launch_bounds__(512) void k_conv2(const float* __restrict__ tt, const float* __restrict__ wT,
                                               const float* __restrict__ bias, float* __restrict__ t2){
  __shared__ alignas(16) float ts[16*NN];
  int jt = blockIdx.x, b = blockIdx.y;
  int tid = threadIdx.x;
  int o = tid & 127, jj = tid >> 7;
  for(int i=tid;i<16*NN;i+=512)
    ts[i] = tt[((size_t)b*64 + jt*16)*NN + i];
  __syncthreads();
  float a0 = 0.f, a1 = 0.f, a2 = 0.f, a3 = 0.f;
  for(int ci=0;ci<NN;ci++){
    const float* wc = wT + (size_t)(ci*4)*NN + o;
    const float* tc2 = ts + (jj*4)*NN + ci;
    a0 = fmaf(tc2[0*NN], wc[0*NN], a0);
    a1 = fmaf(tc2[1*NN], wc[1*NN], a1);
    a2 = fmaf(tc2[2*NN], wc[2*NN], a2);
    a3 = fmaf(tc2[3*NN], wc[3*NN], a3);
  }
  int j = jt*4 + jj;
  t2[((size_t)b*NN + o)*16 + j] = (a0 + a1) + (a2 + a3) + bias[o];
}

// ---------------- K_h1: stage-1 conv + fast GELU -> h1g bf16; spline channels inline ----------------
__global__ __launch_bounds__(256) void k_h1(const float* __restrict__ a0, int bbase,
    const float* __restrict__ y64, const float* __restrict__ M64,
    const float* __restrict__ y16, const float* __restrict__ M16,
    const float* __restrict__ w0, const float* __restrict__ b0,
    const float* __restrict__ w1, const float* __restrict__ b1,
    bf16* __restrict__ h1g){
  constexpr int AY = 10, AX = 36;
  __shared__ alignas(16) float as[3][AY][AX];
  int tid = threadIdx.x;
  int l0 = blockIdx.x*8, n0 = blockIdx.y*32, brel = blockIdx.z, b = bbase + brel;
  float* asf = &as[0][0][0];
  for(int i=tid;i<3*AY*AX;i+=256){
    int ch = i/(AY*AX), rem = i%(AY*AX), yy = rem/AX, xx = rem%AX;
    int gl = l0 + yy - 1, gn = n0 + xx - 1;
    float v = 0.f;
    if(xx < 34 && gl >= 0 && gl < LL && gn >= 0 && gn < NN){
      if(ch == 0)      v = a0[((size_t)b*LL + gl)*NN + gn];
      else if(ch == 1) v = spline_pt(y64, M64, 64, gl, b, gn);
      else             v = spline_pt(y16, M16, 16, gl, b, gn);
    }
    asf[i] = v;
  }
  int c = tid & 31, qg = tid >> 5;
  float wr[3][3][3];
  #pragma unroll
  for(int ci=0;ci<3;ci++)
    #pragma unroll
    for(int dy=0;dy<3;dy++)
      #pragma unroll
      for(int dx=0;dx<3;dx++){
        float wv = 0.5f*w1[((c*3+ci)*3+dy)*3+dx];
        if(dy==1 && dx==1) wv += 0.5f*w0[c*3+ci];
        wr[ci][dy][dx] = wv;
      }
  float br = 0.5f*(b0[c] + b1[c]);
  __syncthreads();
  for(int q=qg; q<64; q+=8){
    int yy = q >> 3, x0q = (q & 7)*4;
    float win[3][3][6];
    #pragma unroll
    for(int ci=0;ci<3;ci++)
      #pragma unroll
      for(int dy=0;dy<3;dy++){
        float4 r4 = *(const float4*)&as[ci][yy+dy][x0q];
        float2 r2 = *(const float2*)&as[ci][yy+dy][x0q+4];
        win[ci][dy][0]=r4.x; win[ci][dy][1]=r4.y; win[ci][dy][2]=r4.z;
        win[ci][dy][3]=r4.w; win[ci][dy][4]=r2.x; win[ci][dy][5]=r2.y;
      }
    #pragma unroll
    for(int p=0;p<4;p++){
      float s = br;
      #pragma unroll
      for(int ci=0;ci<3;ci++)
        #pragma unroll
        for(int dy=0;dy<3;dy++)
          #pragma unroll
          for(int dx=0;dx<3;dx++)
            s = fmaf(wr[ci][dy][dx], win[ci][dy][p+dx], s);
      float val = gelu_fast(s);
      h1g[(((size_t)brel*LL + l0 + yy)*NN + n0 + x0q + p)*DMC + c] = __float2bfloat16(val);
    }
  }
}

// ---------------- K_h2: stage-2 conv + residual, in-place into a0 ----------------
__device__ __forceinline__ float2 bf2f2(unsigned u){
  float2 r;
  r.x = __uint_as_float(u << 16);
  r.y = __uint_as_float(u & 0xffff0000u);
  return r;
}

__global__ __launch_bounds__(256) void k_h2(const bf16* __restrict__ h1g, int bbase,
    const float* __restrict__ vwsT, const float* __restrict__ vb0, const float* __restrict__ vb1,
    float* __restrict__ a0){
  __shared__ unsigned h1s[10][34][17];
  int tid = threadIdx.x;
  int l0 = blockIdx.x*8, n0 = blockIdx.y*32, brel = blockIdx.z, b = bbase + brel;
  const unsigned* hg = (const unsigned*)h1g;
  for(int i=tid;i<340*16;i+=256){
    int px = i >> 4, cp = i & 15;
    int yy = px/34, xx = px - yy*34;
    int gl = l0 + yy - 1, gn = n0 + xx - 1;
    unsigned u = 0;
    if(gl >= 0 && gl < LL && gn >= 0 && gn < NN)
      u = hg[(((size_t)brel*LL + gl)*NN + gn)*16 + cp];
    h1s[yy][xx][cp] = u;
  }
  __syncthreads();
  int oy = tid >> 5, ox = tid & 31;
  float acc = 0.f;
  #pragma unroll
  for(int dy=0;dy<3;dy++)
    #pragma unroll
    for(int dx=0;dx<3;dx++){
      const unsigned* hp = &h1s[oy+dy][ox+dx][0];
      const float4* wt = (const float4*)(vwsT + (dy*3+dx)*DMC);
      #pragma unroll
      for(int cg=0;cg<8;cg++){
        unsigned u0 = hp[cg*2], u1 = hp[cg*2+1];
        float2 f0 = bf2f2(u0), f1 = bf2f2(u1);
        float4 wv = wt[cg];
        acc = fmaf(f0.x, wv.x, acc);
        acc = fmaf(f0.y, wv.y, acc);
        acc = fmaf(f1.x, wv.z, acc);
        acc = fmaf(f1.y, wv.w, acc);
      }
    }
  size_t idx = ((size_t)b*LL + l0 + oy)*NN + n0 + ox;
  a0[idx] = acc + vb0[0] + vb1[0] + a0[idx];
}

// ---------------- K15: GEMM2, 32x64 tile, register-pipelined + de-normalize ----------------
__global__ __launch_bounds__(256) void k_gemm2(const float* __restrict__ a0, const float* __restrict__ ldw,
    const float* __restrict__ ldb, const float* __restrict__ sp, const float* __restrict__ s2p,
    float* __restrict__ out){
  __shared__ alignas(16) float As[16][36];
  __shared__ alignas(16) float Bs[16][68];
  int tid = threadIdx.x;
  int row0 = blockIdx.x*32, p0 = blockIdx.y*64;
  int b = row0 >> 7, n0 = row0 & 127;
  float acc[2][4] = {};
  int lk = tid & 15, lr = tid >> 4;
  int tr = tid & 15, tc = tid >> 4;
  float ra0, ra1, rb[4];
  {
    const float* ak2 = a0 + ((size_t)b*LL + lk)*NN + n0;
    ra0 = ak2[lr]; ra1 = ak2[lr + 16];
    #pragma unroll
    for(int q=0;q<4;q++) rb[q] = ldw[(size_t)(p0 + lr + 16*q)*LL + lk];
  }
  for(int k0=0;k0<LL;k0+=16){
    As[lk][lr]      = ra0;
    As[lk][lr + 16] = ra1;
    #pragma unroll
    for(int q=0;q<4;q++) Bs[lk][lr + 16*q] = rb[q];
    __syncthreads();
    if(k0 + 16 < LL){
      const float* ak2 = a0 + ((size_t)b*LL + k0 + 16 + lk)*NN + n0;
      ra0 = ak2[lr]; ra1 = ak2[lr + 16];
      #pragma unroll
      for(int q=0;q<4;q++) rb[q] = ldw[(size_t)(p0 + lr + 16*q)*LL + k0 + 16 + lk];
    }
    #pragma unroll
    for(int kk=0;kk<16;kk++){
      float2 av = *(const float2*)&As[kk][2*tr];
      float4 bv = *(const float4*)&Bs[kk][4*tc];
      float aa[2] = {av.x, av.y};
      float bb[4] = {bv.x, bv.y, bv.z, bv.w};
      #pragma unroll
      for(int i=0;i<2;i++)
        #pragma unroll
        for(int j=0;j<4;j++) acc[i][j] = fmaf(aa[i], bb[j], acc[i][j]);
    }
    __syncthreads();
  }
  #pragma unroll
  for(int i=0;i<2;i++){
    int row = row0 + 2*tr + i;
    int bb2 = row >> 7, n = row & 127;
    float ssum = 0.f, s2sum = 0.f;
    #pragma unroll
    for(int tq=0;tq<4;tq++){ ssum += sp[tq*2048 + row]; s2sum += s2p[tq*2048 + row]; }
    float mu = ssum*(1.f/512.f);
    float var = fmaxf(s2sum*(1.f/512.f) - mu*mu, 0.f);
    float sd = sqrtf(var + EPSF);
    #pragma unroll
    for(int j=0;j<4;j++){
      int p = p0 + 4*tc + j;
      float v = (acc[i][j] + ldb[p])*sd + mu;
      out[((size_t)bb2*PREDN + p)*NN + n] = v;
    }
  }
}

extern "C" void kernel_launch(void* const* d_in, const int* in_sizes, int n_in,
                              void* d_out, int out_size, void* d_ws, size_t ws_size,
                              hipStream_t stream){
  (void)in_sizes; (void)n_in; (void)out_size; (void)ws_size;
  const float* batch_x = (const float*)d_in[0];
  const float* le_w  = (const float*)d_in[4];
  const float* le_b  = (const float*)d_in[5];
  const float* c1_w  = (const float*)d_in[6];
  const float* c1_b  = (const float*)d_in[7];
  const float* bn1_g = (const float*)d_in[8];
  const float* bn1_b = (const float*)d_in[9];
  const float* c2_w  = (const float*)d_in[10];
  const float* c2_b  = (const float*)d_in[11];
  const float* bn2_g = (const float*)d_in[12];
  const float* bn2_b = (const float*)d_in[13];
  const float* i1_w0 = (const float*)d_in[14];
  const float* i1_b0 = (const float*)d_in[15];
  const float* i1_w1 = (const float*)d_in[16];
  const float* i1_b1 = (const float*)d_in[17];
  const float* i2_w0 = (const float*)d_in[18];
  const float* i2_b0 = (const float*)d_in[19];
  const float* i2_w1 = (const float*)d_in[20];
  const float* i2_b1 = (const float*)d_in[21];
  const float* ld_w  = (const float*)d_in[22];
  const float* ld_b  = (const float*)d_in[23];
  float* out = (float*)d_out;

  float* ws   = (float*)d_ws;
  float* sp   = ws;                        // 8192
  float* s2p  = sp + 8192;                 // 8192
  float* vwsT = s2p + 8192;                // 288 (+pad)
  float* wT1  = vwsT + 320;                // 196,608
  float* wT2  = wT1 + 196608;              // 65,536
  float* x    = wT2 + 65536;               // 1,572,864
  float* a0   = x + (size_t)BB*NN*LL;      // 1,572,864 (single channel)
  float* t1   = a0 + (size_t)BB*LL*NN;     // 131,072
  float* t1t  = t1 + (size_t)BB*NN*64;     // 131,072
  float* sc1  = t1t + (size_t)BB*64*NN;    // 128
  float* sh1  = sc1 + NN;                  // 128
  float* Msp1 = sh1 + NN;                  // 131,072
  float* t2   = Msp1 + (size_t)BB*64*NN;   // 32,768
  float* t2t  = t2 + (size_t)BB*NN*16;     // 32,768
  float* sc2  = t2t + (size_t)BB*16*NN;    // 128
  float* sh2  = sc2 + NN;                  // 128
  float* Msp2 = sh2 + NN;                  // 32,768
  bf16*  h1g  = (bf16*)(Msp2 + (size_t)BB*16*NN);  // 25.2 MB

  k_pre<<<321, 128, 0, stream>>>(batch_x, i2_w0, i2_w1, c1_w, c2_w, sp, s2p, vwsT, wT1, wT2);
  k_gemm1<<<dim3(32,12), 256, 0, stream>>>(batch_x, le_w, le_b, sp, s2p, x, a0);
  k_conv1<<<dim3(16,BB), 512, 0, stream>>>(x, wT1, c1_b, t1);
  k_bnstats<<<NN, 256, 0, stream>>>(t1, bn1_g, bn1_b, BB, 64, sc1, sh1);
  k_bnelu_t<<<dim3(64,BB), NN, 0, stream>>>(t1, sc1, sh1, 64, t1t);
  k_spline_solve<64><<<BB, NN, 0, stream>>>(t1t, Msp1);
  k_conv2<<<dim3(4,BB), 512, 0, stream>>>(t1t, wT2, c2_b, t2);
  k_bnstats<<<NN, 256, 0, stream>>>(t2, bn2_g, bn2_b, BB, 16, sc2, sh2);
  k_bnelu_t<<<dim3(16,BB), NN, 0, stream>>>(t2, sc2, sh2, 16, t2t);
  k_spline_solve<16><<<BB, NN, 0, stream>>>(t2t, Msp2);
  for(int g=0; g<BB; g+=4){
    k_h1<<<dim3(96,4,4), 256, 0, stream>>>(a0, g, t1t, Msp1, t2t, Msp2,
                                           i1_w0, i1_b0, i1_w1, i1_b1, h1g);
    k_h2<<<dim3(96,4,4), 256, 0, stream>>>(h1g, g, vwsT, i2_b0, i2_b1, a0);
  }
  k_gemm2<<<dim3(64,4), 256, 0, stream>>>(a0, ld_w, ld_b, sp, s2p, out);
}

// Round 16
// 360.023 us; speedup vs baseline: 1.1145x; 1.0533x over previous
//
#include <hip/hip_runtime.h>
#include <hip/hip_bf16.h>
#include <math.h>

#define BB 16
#define TT 512
#define NN 128
#define PREDN 256
#define DMC 32
#define LL 768
constexpr float EPSF = 1e-5f;
using bf16 = __hip_bfloat16;
using frag_ab = __attribute__((ext_vector_type(8))) short;   // 8 bf16
using frag_cd = __attribute__((ext_vector_type(4))) float;   // 4 f32

__device__ __forceinline__ unsigned pbf2(float a, float b){
  union { bf16 h; unsigned short u; } x, y;
  x.h = __float2bfloat16(a); y.h = __float2bfloat16(b);
  return (unsigned)x.u | ((unsigned)y.u << 16);
}

__device__ __forceinline__ float gelu_fast(float s){
  float s2v = s*s;
  float e = exp2f(s*fmaf(s2v, 0.10294396f, 2.30211806f));
  return s*e*__builtin_amdgcn_rcpf(e + 1.f);
}

// ---------------- K_pre: stats partials + weight fold + conv weight transposes ----------------
__global__ void k_pre(const float* __restrict__ bx, const float* __restrict__ v0,
                      const float* __restrict__ v1, const float* __restrict__ w1c,
                      const float* __restrict__ w2c, float* __restrict__ sp,
                      float* __restrict__ s2p, float* __restrict__ vwsT,
                      float* __restrict__ wT1, float* __restrict__ wT2){
  int blk = blockIdx.x;
  if(blk < 64){
    int b = blk >> 2, tq = blk & 3, n = threadIdx.x;
    const float* p = bx + (size_t)b*TT*NN + (size_t)tq*128*NN + n;
    float s = 0.f, s2 = 0.f;
    for(int t=0;t<128;t++){ float v = p[(size_t)t*NN]; s += v; s2 += v*v; }
    sp[tq*2048 + b*NN + n] = s;
    s2p[tq*2048 + b*NN + n] = s2;
  } else if(blk == 64){
    for(int i=threadIdx.x; i<9*DMC; i+=blockDim.x){
      int tap = i/DMC, c = i%DMC;
      float wv = 0.5f*v1[c*9 + tap];
      if(tap == 4) wv += 0.5f*v0[c];
      vwsT[i] = wv;
    }
  } else if(blk <= 192){
    int o = blk - 65;
    for(int k=threadIdx.x; k<1536; k+=blockDim.x)
      wT1[(size_t)k*NN + o] = w1c[(size_t)o*1536 + k];
  } else {
    int o = blk - 193;
    for(int k=threadIdx.x; k<512; k+=blockDim.x)
      wT2[(size_t)k*NN + o] = w2c[(size_t)o*512 + k];
  }
}

// ---------------- K1: GEMM1 via bf16 MFMA 16x16x32, 64x64 tile, fused norm + dual store ----------------
// A[m=(b,n)][k=t] = (bx - mu)*rs (bf16), B[n=l][k=t] = lew (bf16). D: col=lane&15, row=quad*4+reg.
__global__ __launch_bounds__(256) void k_gemm1(const float* __restrict__ bx, const float* __restrict__ lew,
    const float* __restrict__ leb, const float* __restrict__ sp, const float* __restrict__ s2p,
    float* __restrict__ x, float* __restrict__ a0){
  __shared__ unsigned Asu[64*20];   // [row 0..63][k-pair 0..15], stride 20 dwords (40 bf16)
  __shared__ unsigned Bsu[64*20];
  int tid = threadIdx.x;
  int row0 = blockIdx.x*64, l0 = blockIdx.y*64;
  int b = row0 >> 7, n0 = row0 & 127;
  int lane = tid & 63, wv = tid >> 6;
  frag_cd acc[4] = {};
  // A loader: n = tid&63, k-span = (tid>>6)*8 .. +7
  int an = tid & 63, akq = (tid >> 6)*8;
  float mu_a, rs_a;
  {
    int rowa = row0 + an;
    float ssum = 0.f, s2sum = 0.f;
    #pragma unroll
    for(int tq=0;tq<4;tq++){ ssum += sp[tq*2048 + rowa]; s2sum += s2p[tq*2048 + rowa]; }
    mu_a = ssum*(1.f/512.f);
    rs_a = 1.f/sqrtf(fmaxf(s2sum*(1.f/512.f) - mu_a*mu_a, 0.f) + EPSF);
  }
  // B loader: tk = tid&15 (k-pair), blc = tid>>4 (l col base), 4 passes
  int btk = tid & 15, blc = tid >> 4;
  unsigned ra[4], rbq[4];
  // prefetch k0 = 0
  #pragma unroll
  for(int u=0;u<4;u++){
    float v0 = (bx[((size_t)b*TT + akq + 2*u)*NN + n0 + an] - mu_a)*rs_a;
    float v1 = (bx[((size_t)b*TT + akq + 2*u + 1)*NN + n0 + an] - mu_a)*rs_a;
    ra[u] = pbf2(v0, v1);
    const float* lp = lew + (size_t)(l0 + blc + 16*u)*TT + 2*btk;
    rbq[u] = pbf2(lp[0], lp[1]);
  }
  int fr = wv*16 + (lane & 15);        // A frag row
  int fq = (lane >> 4)*4;              // frag dword offset (k-pair)
  for(int k0=0;k0<TT;k0+=32){
    *(uint4*)&Asu[an*20 + (akq>>1)] = make_uint4(ra[0], ra[1], ra[2], ra[3]);
    #pragma unroll
    for(int p=0;p<4;p++) Bsu[(blc + 16*p)*20 + btk] = rbq[p];
    __syncthreads();
    if(k0 + 32 < TT){
      #pragma unroll
      for(int u=0;u<4;u++){
        float v0 = (bx[((size_t)b*TT + k0 + 32 + akq + 2*u)*NN + n0 + an] - mu_a)*rs_a;
        float v1 = (bx[((size_t)b*TT + k0 + 32 + akq + 2*u + 1)*NN + n0 + an] - mu_a)*rs_a;
        ra[u] = pbf2(v0, v1);
        const float* lp = lew + (size_t)(l0 + blc + 16*u)*TT + k0 + 32 + 2*btk;
        rbq[u] = pbf2(lp[0], lp[1]);
      }
    }
    frag_ab af = *(const frag_ab*)&Asu[fr*20 + fq];
    #pragma unroll
    for(int nt=0;nt<4;nt++){
      frag_ab bf = *(const frag_ab*)&Bsu[(nt*16 + (lane & 15))*20 + fq];
      acc[nt] = __builtin_amdgcn_mfma_f32_16x16x32_bf16(af, bf, acc[nt], 0, 0, 0);
    }
    __syncthreads();
  }
  int col = lane & 15, quad = lane >> 4;
  #pragma unroll
  for(int nt=0;nt<4;nt++){
    int l = l0 + nt*16 + col;
    float lb = leb[l];
    #pragma unroll
    for(int r=0;r<4;r++){
      int m = wv*16 + quad*4 + r;
      x[(size_t)(row0 + m)*LL + l] = acc[nt][r] + lb;
    }
    float4 st;
    st.x = acc[nt][0] + lb;
    st.y = acc[nt][1] + lb;
    st.z = acc[nt][2] + lb;
    st.w = acc[nt][3] + lb;
    *(float4*)&a0[((size_t)b*LL + l)*NN + n0 + wv*16 + quad*4] = st;
  }
}

// ---------------- K3: conv1 (coalesced wT, 4 j per block) ----------------
__global__ __launch_bounds__(512) void k_conv1(const float* __restrict__ x, const float* __restrict__ wT,
                                               const float* __restrict__ bias, float* __restrict__ t1){
  __shared__ alignas(16) float xs[NN*48];
  int jt = blockIdx.x, b = blockIdx.y;
  int tid = threadIdx.x;
  int o = tid & 127, jj = tid >> 7;
  for(int i=tid;i<NN*48;i+=512){
    int ci = i/48, kk = i%48;
    xs[i] = x[((size_t)b*NN + ci)*LL + jt*48 + kk];
  }
  __syncthreads();
  float a0 = 0.f, a1 = 0.f, a2 = 0.f, a3 = 0.f;
  for(int ci=0;ci<NN;ci++){
    const float* xc = xs + ci*48 + jj*12;
    const float* wc = wT + (size_t)(ci*12)*NN + o;
    #pragma unroll
    for(int kk=0;kk<12;kk+=4){
      a0 = fmaf(xc[kk+0], wc[(size_t)(kk+0)*NN], a0);
      a1 = fmaf(xc[kk+1], wc[(size_t)(kk+1)*NN], a1);
      a2 = fmaf(xc[kk+2], wc[(size_t)(kk+2)*NN], a2);
      a3 = fmaf(xc[kk+3], wc[(size_t)(kk+3)*NN], a3);
    }
  }
  int j = jt*4 + jj;
  t1[((size_t)b*NN + o)*64 + j] = (a0 + a1) + (a2 + a3) + bias[o];
}

// ---------------- K4: BN stats per channel ----------------
__global__ void k_bnstats(const float* __restrict__ t, const float* __restrict__ g, const float* __restrict__ bb,
                          int Bcnt, int Jcnt, float* __restrict__ scale, float* __restrict__ shift){
  int o = blockIdx.x;
  int tot = Bcnt*Jcnt;
  float s = 0.f, s2 = 0.f;
  for(int i=threadIdx.x; i<tot; i+=blockDim.x){
    int b = i / Jcnt, j = i % Jcnt;
    float v = t[((size_t)b*NN + o)*Jcnt + j];
    s += v; s2 += v*v;
  }
  __shared__ float rs[256], rs2[256];
  rs[threadIdx.x] = s; rs2[threadIdx.x] = s2;
  __syncthreads();
  for(int st=128; st>0; st>>=1){
    if(threadIdx.x < st){ rs[threadIdx.x] += rs[threadIdx.x+st]; rs2[threadIdx.x] += rs2[threadIdx.x+st]; }
    __syncthreads();
  }
  if(threadIdx.x == 0){
    float mu = rs[0]/tot;
    float var = fmaxf(rs2[0]/tot - mu*mu, 0.f);
    float sc = g[o] * rsqrtf(var + EPSF);
    scale[o] = sc; shift[o] = bb[o] - mu*sc;
  }
}

// ---------------- K5: BN apply + ELU + transpose ----------------
__global__ void k_bnelu_t(const float* __restrict__ t, const float* __restrict__ scale,
                          const float* __restrict__ shift, int Jcnt, float* __restrict__ tt){
  int j = blockIdx.x, b = blockIdx.y, o = threadIdx.x;
  float v = t[((size_t)b*NN + o)*Jcnt + j]*scale[o] + shift[o];
  v = v > 0.f ? v : (expf(v) - 1.f);
  tt[((size_t)b*Jcnt + j)*NN + o] = v;
}

// ---------------- K6: spline tridiagonal solve (Thomas) ----------------
template<int LK>
__global__ void k_spline_solve(const float* __restrict__ y, float* __restrict__ M){
  constexpr int m = LK-2;
  const float Kc = 6.f*(LK-1)*(LK-1);
  __shared__ float cp[m];
  __shared__ float dp[m][NN];
  int b = blockIdx.x, c = threadIdx.x;
  if(c == 0){
    float cv = 0.25f; cp[0] = cv;
    for(int i=1;i<m;i++){ cv = 1.f/(4.f - cv); cp[i] = cv; }
  }
  __syncthreads();
  const float* yb = y + (size_t)b*LK*NN + c;
  float y0 = yb[0], y1 = yb[NN];
  float dprev = 0.f;
  for(int i=0;i<m;i++){
    float y2 = yb[(size_t)(i+2)*NN];
    float r = (y2 - 2.f*y1 + y0)*Kc;
    float d = (i == 0) ? r*0.25f : (r - dprev)*cp[i];
    dp[i][c] = d; dprev = d;
    y0 = y1; y1 = y2;
  }
  float* Mb = M + (size_t)b*LK*NN + c;
  float xv = dp[m-1][c];
  Mb[(size_t)m*NN] = xv;
  for(int i=m-2;i>=0;i--){
    xv = dp[i][c] - cp[i]*xv;
    Mb[(size_t)(i+1)*NN] = xv;
  }
  Mb[0] = 0.f;
  Mb[(size_t)(LK-1)*NN] = 0.f;
}

// ---------------- spline point evaluation (device) ----------------
__device__ __forceinline__ float spline_pt(const float* __restrict__ y, const float* __restrict__ M,
                                           int LK, int l, int b, int c){
  float hh = 1.f/(LK-1);
  float q = (float)l * (1.f/(LL-1));
  int idx = (int)floorf(q*(LK-1));
  if(idx > LK-2) idx = LK-2;
  float s = q - idx*hh;
  float u = hh - s;
  const float* yb = y + ((size_t)b*LK + idx)*NN + c;
  const float* Mb = M + ((size_t)b*LK + idx)*NN + c;
  float yi = yb[0], yi1 = yb[NN], M0 = Mb[0], M1 = Mb[NN];
  float hh6 = hh*hh/6.f;
  return (M0*u*u*u + M1*s*s*s)*(1.f/(6.f*hh))
       + (yi  - M0*hh6)*(u*(1.f/hh))
       + (yi1 - M1*hh6)*(s*(1.f/hh));
}

// ---------------- K8: conv2 (coalesced wT, 4 j per block) ----------------
__global__ __launch_bounds__(512) void k_conv2(const float* __restrict__ tt, const float* __restrict__ wT,
                                               const float* __restrict__ bias, float* __restrict__ t2){
  __shared__ alignas(16) float ts[16*NN];
  int jt = blockIdx.x, b = blockIdx.y;
  int tid = threadIdx.x;
  int o = tid & 127, jj = tid >> 7;
  for(int i=tid;i<16*NN;i+=512)
    ts[i] = tt[((size_t)b*64 + jt*16)*NN + i];
  __syncthreads();
  float a0 = 0.f, a1 = 0.f, a2 = 0.f, a3 = 0.f;
  for(int ci=0;ci<NN;ci++){
    const float* wc = wT + (size_t)(ci*4)*NN + o;
    const float* tc2 = ts + (jj*4)*NN + ci;
    a0 = fmaf(tc2[0*NN], wc[0*NN], a0);
    a1 = fmaf(tc2[1*NN], wc[1*NN], a1);
    a2 = fmaf(tc2[2*NN], wc[2*NN], a2);
    a3 = fmaf(tc2[3*NN], wc[3*NN], a3);
  }
  int j = jt*4 + jj;
  t2[((size_t)b*NN + o)*16 + j] = (a0 + a1) + (a2 + a3) + bias[o];
}

// ---------------- K_h1: stage-1 conv + fast GELU -> h1g bf16; spline channels inline ----------------
__global__ __launch_bounds__(256) void k_h1(const float* __restrict__ a0, int bbase,
    const float* __restrict__ y64, const float* __restrict__ M64,
    const float* __restrict__ y16, const float* __restrict__ M16,
    const float* __restrict__ w0, const float* __restrict__ b0,
    const float* __restrict__ w1, const float* __restrict__ b1,
    bf16* __restrict__ h1g){
  constexpr int AY = 10, AX = 36;
  __shared__ alignas(16) float as[3][AY][AX];
  int tid = threadIdx.x;
  int l0 = blockIdx.x*8, n0 = blockIdx.y*32, brel = blockIdx.z, b = bbase + brel;
  float* asf = &as[0][0][0];
  for(int i=tid;i<3*AY*AX;i+=256){
    int ch = i/(AY*AX), rem = i%(AY*AX), yy = rem/AX, xx = rem%AX;
    int gl = l0 + yy - 1, gn = n0 + xx - 1;
    float v = 0.f;
    if(xx < 34 && gl >= 0 && gl < LL && gn >= 0 && gn < NN){
      if(ch == 0)      v = a0[((size_t)b*LL + gl)*NN + gn];
      else if(ch == 1) v = spline_pt(y64, M64, 64, gl, b, gn);
      else             v = spline_pt(y16, M16, 16, gl, b, gn);
    }
    asf[i] = v;
  }
  int c = tid & 31, qg = tid >> 5;
  float wr[3][3][3];
  #pragma unroll
  for(int ci=0;ci<3;ci++)
    #pragma unroll
    for(int dy=0;dy<3;dy++)
      #pragma unroll
      for(int dx=0;dx<3;dx++){
        float wv = 0.5f*w1[((c*3+ci)*3+dy)*3+dx];
        if(dy==1 && dx==1) wv += 0.5f*w0[c*3+ci];
        wr[ci][dy][dx] = wv;
      }
  float br = 0.5f*(b0[c] + b1[c]);
  __syncthreads();
  for(int q=qg; q<64; q+=8){
    int yy = q >> 3, x0q = (q & 7)*4;
    float win[3][3][6];
    #pragma unroll
    for(int ci=0;ci<3;ci++)
      #pragma unroll
      for(int dy=0;dy<3;dy++){
        float4 r4 = *(const float4*)&as[ci][yy+dy][x0q];
        float2 r2 = *(const float2*)&as[ci][yy+dy][x0q+4];
        win[ci][dy][0]=r4.x; win[ci][dy][1]=r4.y; win[ci][dy][2]=r4.z;
        win[ci][dy][3]=r4.w; win[ci][dy][4]=r2.x; win[ci][dy][5]=r2.y;
      }
    #pragma unroll
    for(int p=0;p<4;p++){
      float s = br;
      #pragma unroll
      for(int ci=0;ci<3;ci++)
        #pragma unroll
        for(int dy=0;dy<3;dy++)
          #pragma unroll
          for(int dx=0;dx<3;dx++)
            s = fmaf(wr[ci][dy][dx], win[ci][dy][p+dx], s);
      float val = gelu_fast(s);
      h1g[(((size_t)brel*LL + l0 + yy)*NN + n0 + x0q + p)*DMC + c] = __float2bfloat16(val);
    }
  }
}

// ---------------- K_h2: stage-2 conv + residual, in-place into a0 ----------------
__device__ __forceinline__ float2 bf2f2(unsigned u){
  float2 r;
  r.x = __uint_as_float(u << 16);
  r.y = __uint_as_float(u & 0xffff0000u);
  return r;
}

__global__ __launch_bounds__(256) void k_h2(const bf16* __restrict__ h1g, int bbase,
    const float* __restrict__ vwsT, const float* __restrict__ vb0, const float* __restrict__ vb1,
    float* __restrict__ a0){
  __shared__ unsigned h1s[10][34][17];
  int tid = threadIdx.x;
  int l0 = blockIdx.x*8, n0 = blockIdx.y*32, brel = blockIdx.z, b = bbase + brel;
  const unsigned* hg = (const unsigned*)h1g;
  for(int i=tid;i<340*16;i+=256){
    int px = i >> 4, cp = i & 15;
    int yy = px/34, xx = px - yy*34;
    int gl = l0 + yy - 1, gn = n0 + xx - 1;
    unsigned u = 0;
    if(gl >= 0 && gl < LL && gn >= 0 && gn < NN)
      u = hg[(((size_t)brel*LL + gl)*NN + gn)*16 + cp];
    h1s[yy][xx][cp] = u;
  }
  __syncthreads();
  int oy = tid >> 5, ox = tid & 31;
  float acc = 0.f;
  #pragma unroll
  for(int dy=0;dy<3;dy++)
    #pragma unroll
    for(int dx=0;dx<3;dx++){
      const unsigned* hp = &h1s[oy+dy][ox+dx][0];
      const float4* wt = (const float4*)(vwsT + (dy*3+dx)*DMC);
      #pragma unroll
      for(int cg=0;cg<8;cg++){
        unsigned u0 = hp[cg*2], u1 = hp[cg*2+1];
        float2 f0 = bf2f2(u0), f1 = bf2f2(u1);
        float4 wv = wt[cg];
        acc = fmaf(f0.x, wv.x, acc);
        acc = fmaf(f0.y, wv.y, acc);
        acc = fmaf(f1.x, wv.z, acc);
        acc = fmaf(f1.y, wv.w, acc);
      }
    }
  size_t idx = ((size_t)b*LL + l0 + oy)*NN + n0 + ox;
  a0[idx] = acc + vb0[0] + vb1[0] + a0[idx];
}

// ---------------- K15: GEMM2, 32x64 tile, register-pipelined + de-normalize ----------------
__global__ __launch_bounds__(256) void k_gemm2(const float* __restrict__ a0, const float* __restrict__ ldw,
    const float* __restrict__ ldb, const float* __restrict__ sp, const float* __restrict__ s2p,
    float* __restrict__ out){
  __shared__ alignas(16) float As[16][36];
  __shared__ alignas(16) float Bs[16][68];
  int tid = threadIdx.x;
  int row0 = blockIdx.x*32, p0 = blockIdx.y*64;
  int b = row0 >> 7, n0 = row0 & 127;
  float acc[2][4] = {};
  int lk = tid & 15, lr = tid >> 4;
  int tr = tid & 15, tc = tid >> 4;
  float ra0, ra1, rb[4];
  {
    const float* ak2 = a0 + ((size_t)b*LL + lk)*NN + n0;
    ra0 = ak2[lr]; ra1 = ak2[lr + 16];
    #pragma unroll
    for(int q=0;q<4;q++) rb[q] = ldw[(size_t)(p0 + lr + 16*q)*LL + lk];
  }
  for(int k0=0;k0<LL;k0+=16){
    As[lk][lr]      = ra0;
    As[lk][lr + 16] = ra1;
    #pragma unroll
    for(int q=0;q<4;q++) Bs[lk][lr + 16*q] = rb[q];
    __syncthreads();
    if(k0 + 16 < LL){
      const float* ak2 = a0 + ((size_t)b*LL + k0 + 16 + lk)*NN + n0;
      ra0 = ak2[lr]; ra1 = ak2[lr + 16];
      #pragma unroll
      for(int q=0;q<4;q++) rb[q] = ldw[(size_t)(p0 + lr + 16*q)*LL + k0 + 16 + lk];
    }
    #pragma unroll
    for(int kk=0;kk<16;kk++){
      float2 av = *(const float2*)&As[kk][2*tr];
      float4 bv = *(const float4*)&Bs[kk][4*tc];
      float aa[2] = {av.x, av.y};
      float bb[4] = {bv.x, bv.y, bv.z, bv.w};
      #pragma unroll
      for(int i=0;i<2;i++)
        #pragma unroll
        for(int j=0;j<4;j++) acc[i][j] = fmaf(aa[i], bb[j], acc[i][j]);
    }
    __syncthreads();
  }
  #pragma unroll
  for(int i=0;i<2;i++){
    int row = row0 + 2*tr + i;
    int bb2 = row >> 7, n = row & 127;
    float ssum = 0.f, s2sum = 0.f;
    #pragma unroll
    for(int tq=0;tq<4;tq++){ ssum += sp[tq*2048 + row]; s2sum += s2p[tq*2048 + row]; }
    float mu = ssum*(1.f/512.f);
    float var = fmaxf(s2sum*(1.f/512.f) - mu*mu, 0.f);
    float sd = sqrtf(var + EPSF);
    #pragma unroll
    for(int j=0;j<4;j++){
      int p = p0 + 4*tc + j;
      float v = (acc[i][j] + ldb[p])*sd + mu;
      out[((size_t)bb2*PREDN + p)*NN + n] = v;
    }
  }
}

extern "C" void kernel_launch(void* const* d_in, const int* in_sizes, int n_in,
                              void* d_out, int out_size, void* d_ws, size_t ws_size,
                              hipStream_t stream){
  (void)in_sizes; (void)n_in; (void)out_size; (void)ws_size;
  const float* batch_x = (const float*)d_in[0];
  const float* le_w  = (const float*)d_in[4];
  const float* le_b  = (const float*)d_in[5];
  const float* c1_w  = (const float*)d_in[6];
  const float* c1_b  = (const float*)d_in[7];
  const float* bn1_g = (const float*)d_in[8];
  const float* bn1_b = (const float*)d_in[9];
  const float* c2_w  = (const float*)d_in[10];
  const float* c2_b  = (const float*)d_in[11];
  const float* bn2_g = (const float*)d_in[12];
  const float* bn2_b = (const float*)d_in[13];
  const float* i1_w0 = (const float*)d_in[14];
  const float* i1_b0 = (const float*)d_in[15];
  const float* i1_w1 = (const float*)d_in[16];
  const float* i1_b1 = (const float*)d_in[17];
  const float* i2_w0 = (const float*)d_in[18];
  const float* i2_b0 = (const float*)d_in[19];
  const float* i2_w1 = (const float*)d_in[20];
  const float* i2_b1 = (const float*)d_in[21];
  const float* ld_w  = (const float*)d_in[22];
  const float* ld_b  = (const float*)d_in[23];
  float* out = (float*)d_out;

  float* ws   = (float*)d_ws;
  float* sp   = ws;                        // 8192
  float* s2p  = sp + 8192;                 // 8192
  float* vwsT = s2p + 8192;                // 288 (+pad)
  float* wT1  = vwsT + 320;                // 196,608
  float* wT2  = wT1 + 196608;              // 65,536
  float* x    = wT2 + 65536;               // 1,572,864
  float* a0   = x + (size_t)BB*NN*LL;      // 1,572,864
  float* t1   = a0 + (size_t)BB*LL*NN;     // 131,072
  float* t1t  = t1 + (size_t)BB*NN*64;     // 131,072
  float* sc1  = t1t + (size_t)BB*64*NN;    // 128
  float* sh1  = sc1 + NN;                  // 128
  float* Msp1 = sh1 + NN;                  // 131,072
  float* t2   = Msp1 + (size_t)BB*64*NN;   // 32,768
  float* t2t  = t2 + (size_t)BB*NN*16;     // 32,768
  float* sc2  = t2t + (size_t)BB*16*NN;    // 128
  float* sh2  = sc2 + NN;                  // 128
  float* Msp2 = sh2 + NN;                  // 32,768
  bf16*  h1g  = (bf16*)(Msp2 + (size_t)BB*16*NN);  // 25.2 MB

  k_pre<<<321, 128, 0, stream>>>(batch_x, i2_w0, i2_w1, c1_w, c2_w, sp, s2p, vwsT, wT1, wT2);
  k_gemm1<<<dim3(32,12), 256, 0, stream>>>(batch_x, le_w, le_b, sp, s2p, x, a0);
  k_conv1<<<dim3(16,BB), 512, 0, stream>>>(x, wT1, c1_b, t1);
  k_bnstats<<<NN, 256, 0, stream>>>(t1, bn1_g, bn1_b, BB, 64, sc1, sh1);
  k_bnelu_t<<<dim3(64,BB), NN, 0, stream>>>(t1, sc1, sh1, 64, t1t);
  k_spline_solve<64><<<BB, NN, 0, stream>>>(t1t, Msp1);
  k_conv2<<<dim3(4,BB), 512, 0, stream>>>(t1t, wT2, c2_b, t2);
  k_bnstats<<<NN, 256, 0, stream>>>(t2, bn2_g, bn2_b, BB, 16, sc2, sh2);
  k_bnelu_t<<<dim3(16,BB), NN, 0, stream>>>(t2, sc2, sh2, 16, t2t);
  k_spline_solve<16><<<BB, NN, 0, stream>>>(t2t, Msp2);
  for(int g=0; g<BB; g+=4){
    k_h1<<<dim3(96,4,4), 256, 0, stream>>>(a0, g, t1t, Msp1, t2t, Msp2,
                                           i1_w0, i1_b0, i1_w1, i1_b1, h1g);
    k_h2<<<dim3(96,4,4), 256, 0, stream>>>(h1g, g, vwsT, i2_b0, i2_b1, a0);
  }
  k_gemm2<<<dim3(64,4), 256, 0, stream>>>(a0, ld_w, ld_b, sp, s2p, out);
}

// Round 17
// 322.997 us; speedup vs baseline: 1.2423x; 1.1146x over previous
//
#include <hip/hip_runtime.h>
#include <hip/hip_bf16.h>
#include <math.h>

#define BB 16
#define TT 512
#define NN 128
#define PREDN 256
#define DMC 32
#define LL 768
constexpr float EPSF = 1e-5f;
using bf16 = __hip_bfloat16;
using frag_ab = __attribute__((ext_vector_type(8))) short;   // 8 bf16
using frag_cd = __attribute__((ext_vector_type(4))) float;   // 4 f32

__device__ __forceinline__ unsigned pbf2(float a, float b){
  union { bf16 h; unsigned short u; } x, y;
  x.h = __float2bfloat16(a); y.h = __float2bfloat16(b);
  return (unsigned)x.u | ((unsigned)y.u << 16);
}

__device__ __forceinline__ float gelu_fast(float s){
  float s2v = s*s;
  float e = exp2f(s*fmaf(s2v, 0.10294396f, 2.30211806f));
  return s*e*__builtin_amdgcn_rcpf(e + 1.f);
}

// ---------------- K_pre: stats partials + weight fold + conv weight transposes ----------------
__global__ void k_pre(const float* __restrict__ bx, const float* __restrict__ v0,
                      const float* __restrict__ v1, const float* __restrict__ w1c,
                      const float* __restrict__ w2c, float* __restrict__ sp,
                      float* __restrict__ s2p, float* __restrict__ vwsT,
                      float* __restrict__ wT1, float* __restrict__ wT2){
  int blk = blockIdx.x;
  if(blk < 64){
    int b = blk >> 2, tq = blk & 3, n = threadIdx.x;
    const float* p = bx + (size_t)b*TT*NN + (size_t)tq*128*NN + n;
    float s = 0.f, s2 = 0.f;
    for(int t=0;t<128;t++){ float v = p[(size_t)t*NN]; s += v; s2 += v*v; }
    sp[tq*2048 + b*NN + n] = s;
    s2p[tq*2048 + b*NN + n] = s2;
  } else if(blk == 64){
    for(int i=threadIdx.x; i<9*DMC; i+=blockDim.x){
      int tap = i/DMC, c = i%DMC;
      float wv = 0.5f*v1[c*9 + tap];
      if(tap == 4) wv += 0.5f*v0[c];
      vwsT[i] = wv;
    }
  } else if(blk <= 192){
    int o = blk - 65;
    for(int k=threadIdx.x; k<1536; k+=blockDim.x)
      wT1[(size_t)k*NN + o] = w1c[(size_t)o*1536 + k];
  } else {
    int o = blk - 193;
    for(int k=threadIdx.x; k<512; k+=blockDim.x)
      wT2[(size_t)k*NN + o] = w2c[(size_t)o*512 + k];
  }
}

// ---------------- K1: GEMM1 via bf16 MFMA 16x16x32, 64x64 tile, fused norm + dual store ----------------
__global__ __launch_bounds__(256) void k_gemm1(const float* __restrict__ bx, const float* __restrict__ lew,
    const float* __restrict__ leb, const float* __restrict__ sp, const float* __restrict__ s2p,
    float* __restrict__ x, float* __restrict__ a0){
  __shared__ unsigned Asu[64*20];
  __shared__ unsigned Bsu[64*20];
  int tid = threadIdx.x;
  int row0 = blockIdx.x*64, l0 = blockIdx.y*64;
  int b = row0 >> 7, n0 = row0 & 127;
  int lane = tid & 63, wv = tid >> 6;
  frag_cd acc[4] = {};
  int an = tid & 63, akq = (tid >> 6)*8;
  float mu_a, rs_a;
  {
    int rowa = row0 + an;
    float ssum = 0.f, s2sum = 0.f;
    #pragma unroll
    for(int tq=0;tq<4;tq++){ ssum += sp[tq*2048 + rowa]; s2sum += s2p[tq*2048 + rowa]; }
    mu_a = ssum*(1.f/512.f);
    rs_a = 1.f/sqrtf(fmaxf(s2sum*(1.f/512.f) - mu_a*mu_a, 0.f) + EPSF);
  }
  int btk = tid & 15, blc = tid >> 4;
  unsigned ra[4], rbq[4];
  #pragma unroll
  for(int u=0;u<4;u++){
    float v0 = (bx[((size_t)b*TT + akq + 2*u)*NN + n0 + an] - mu_a)*rs_a;
    float v1 = (bx[((size_t)b*TT + akq + 2*u + 1)*NN + n0 + an] - mu_a)*rs_a;
    ra[u] = pbf2(v0, v1);
    const float* lp = lew + (size_t)(l0 + blc + 16*u)*TT + 2*btk;
    rbq[u] = pbf2(lp[0], lp[1]);
  }
  int fr = wv*16 + (lane & 15);
  int fq = (lane >> 4)*4;
  for(int k0=0;k0<TT;k0+=32){
    *(uint4*)&Asu[an*20 + (akq>>1)] = make_uint4(ra[0], ra[1], ra[2], ra[3]);
    #pragma unroll
    for(int p=0;p<4;p++) Bsu[(blc + 16*p)*20 + btk] = rbq[p];
    __syncthreads();
    if(k0 + 32 < TT){
      #pragma unroll
      for(int u=0;u<4;u++){
        float v0 = (bx[((size_t)b*TT + k0 + 32 + akq + 2*u)*NN + n0 + an] - mu_a)*rs_a;
        float v1 = (bx[((size_t)b*TT + k0 + 32 + akq + 2*u + 1)*NN + n0 + an] - mu_a)*rs_a;
        ra[u] = pbf2(v0, v1);
        const float* lp = lew + (size_t)(l0 + blc + 16*u)*TT + k0 + 32 + 2*btk;
        rbq[u] = pbf2(lp[0], lp[1]);
      }
    }
    frag_ab af = *(const frag_ab*)&Asu[fr*20 + fq];
    #pragma unroll
    for(int nt=0;nt<4;nt++){
      frag_ab bf = *(const frag_ab*)&Bsu[(nt*16 + (lane & 15))*20 + fq];
      acc[nt] = __builtin_amdgcn_mfma_f32_16x16x32_bf16(af, bf, acc[nt], 0, 0, 0);
    }
    __syncthreads();
  }
  int col = lane & 15, quad = lane >> 4;
  #pragma unroll
  for(int nt=0;nt<4;nt++){
    int l = l0 + nt*16 + col;
    float lb = leb[l];
    #pragma unroll
    for(int r=0;r<4;r++){
      int m = wv*16 + quad*4 + r;
      x[(size_t)(row0 + m)*LL + l] = acc[nt][r] + lb;
    }
    float4 st;
    st.x = acc[nt][0] + lb;
    st.y = acc[nt][1] + lb;
    st.z = acc[nt][2] + lb;
    st.w = acc[nt][3] + lb;
    *(float4*)&a0[((size_t)b*LL + l)*NN + n0 + wv*16 + quad*4] = st;
  }
}

// ---------------- K3: conv1 (coalesced wT, 4 j per block) ----------------
__global__ __launch_bounds__(512) void k_conv1(const float* __restrict__ x, const float* __restrict__ wT,
                                               const float* __restrict__ bias, float* __restrict__ t1){
  __shared__ alignas(16) float xs[NN*48];
  int jt = blockIdx.x, b = blockIdx.y;
  int tid = threadIdx.x;
  int o = tid & 127, jj = tid >> 7;
  for(int i=tid;i<NN*48;i+=512){
    int ci = i/48, kk = i%48;
    xs[i] = x[((size_t)b*NN + ci)*LL + jt*48 + kk];
  }
  __syncthreads();
  float a0 = 0.f, a1 = 0.f, a2 = 0.f, a3 = 0.f;
  for(int ci=0;ci<NN;ci++){
    const float* xc = xs + ci*48 + jj*12;
    const float* wc = wT + (size_t)(ci*12)*NN + o;
    #pragma unroll
    for(int kk=0;kk<12;kk+=4){
      a0 = fmaf(xc[kk+0], wc[(size_t)(kk+0)*NN], a0);
      a1 = fmaf(xc[kk+1], wc[(size_t)(kk+1)*NN], a1);
      a2 = fmaf(xc[kk+2], wc[(size_t)(kk+2)*NN], a2);
      a3 = fmaf(xc[kk+3], wc[(size_t)(kk+3)*NN], a3);
    }
  }
  int j = jt*4 + jj;
  t1[((size_t)b*NN + o)*64 + j] = (a0 + a1) + (a2 + a3) + bias[o];
}

// ---------------- K4: BN stats per channel ----------------
__global__ void k_bnstats(const float* __restrict__ t, const float* __restrict__ g, const float* __restrict__ bb,
                          int Bcnt, int Jcnt, float* __restrict__ scale, float* __restrict__ shift){
  int o = blockIdx.x;
  int tot = Bcnt*Jcnt;
  float s = 0.f, s2 = 0.f;
  for(int i=threadIdx.x; i<tot; i+=blockDim.x){
    int b = i / Jcnt, j = i % Jcnt;
    float v = t[((size_t)b*NN + o)*Jcnt + j];
    s += v; s2 += v*v;
  }
  __shared__ float rs[256], rs2[256];
  rs[threadIdx.x] = s; rs2[threadIdx.x] = s2;
  __syncthreads();
  for(int st=128; st>0; st>>=1){
    if(threadIdx.x < st){ rs[threadIdx.x] += rs[threadIdx.x+st]; rs2[threadIdx.x] += rs2[threadIdx.x+st]; }
    __syncthreads();
  }
  if(threadIdx.x == 0){
    float mu = rs[0]/tot;
    float var = fmaxf(rs2[0]/tot - mu*mu, 0.f);
    float sc = g[o] * rsqrtf(var + EPSF);
    scale[o] = sc; shift[o] = bb[o] - mu*sc;
  }
}

// ---------------- K5: BN apply + ELU + transpose ----------------
__global__ void k_bnelu_t(const float* __restrict__ t, const float* __restrict__ scale,
                          const float* __restrict__ shift, int Jcnt, float* __restrict__ tt){
  int j = blockIdx.x, b = blockIdx.y, o = threadIdx.x;
  float v = t[((size_t)b*NN + o)*Jcnt + j]*scale[o] + shift[o];
  v = v > 0.f ? v : (expf(v) - 1.f);
  tt[((size_t)b*Jcnt + j)*NN + o] = v;
}

// ---------------- K6: spline tridiagonal solve (Thomas) ----------------
template<int LK>
__global__ void k_spline_solve(const float* __restrict__ y, float* __restrict__ M){
  constexpr int m = LK-2;
  const float Kc = 6.f*(LK-1)*(LK-1);
  __shared__ float cp[m];
  __shared__ float dp[m][NN];
  int b = blockIdx.x, c = threadIdx.x;
  if(c == 0){
    float cv = 0.25f; cp[0] = cv;
    for(int i=1;i<m;i++){ cv = 1.f/(4.f - cv); cp[i] = cv; }
  }
  __syncthreads();
  const float* yb = y + (size_t)b*LK*NN + c;
  float y0 = yb[0], y1 = yb[NN];
  float dprev = 0.f;
  for(int i=0;i<m;i++){
    float y2 = yb[(size_t)(i+2)*NN];
    float r = (y2 - 2.f*y1 + y0)*Kc;
    float d = (i == 0) ? r*0.25f : (r - dprev)*cp[i];
    dp[i][c] = d; dprev = d;
    y0 = y1; y1 = y2;
  }
  float* Mb = M + (size_t)b*LK*NN + c;
  float xv = dp[m-1][c];
  Mb[(size_t)m*NN] = xv;
  for(int i=m-2;i>=0;i--){
    xv = dp[i][c] - cp[i]*xv;
    Mb[(size_t)(i+1)*NN] = xv;
  }
  Mb[0] = 0.f;
  Mb[(size_t)(LK-1)*NN] = 0.f;
}

// ---------------- spline point evaluation (device) ----------------
__device__ __forceinline__ float spline_pt(const float* __restrict__ y, const float* __restrict__ M,
                                           int LK, int l, int b, int c){
  float hh = 1.f/(LK-1);
  float q = (float)l * (1.f/(LL-1));
  int idx = (int)floorf(q*(LK-1));
  if(idx > LK-2) idx = LK-2;
  float s = q - idx*hh;
  float u = hh - s;
  const float* yb = y + ((size_t)b*LK + idx)*NN + c;
  const float* Mb = M + ((size_t)b*LK + idx)*NN + c;
  float yi = yb[0], yi1 = yb[NN], M0 = Mb[0], M1 = Mb[NN];
  float hh6 = hh*hh/6.f;
  return (M0*u*u*u + M1*s*s*s)*(1.f/(6.f*hh))
       + (yi  - M0*hh6)*(u*(1.f/hh))
       + (yi1 - M1*hh6)*(s*(1.f/hh));
}

// ---------------- K8: conv2 (coalesced wT, 4 j per block) ----------------
__global__ __launch_bounds__(512) void k_conv2(const float* __restrict__ tt, const float* __restrict__ wT,
                                               const float* __restrict__ bias, float* __restrict__ t2){
  __shared__ alignas(16) float ts[16*NN];
  int jt = blockIdx.x, b = blockIdx.y;
  int tid = threadIdx.x;
  int o = tid & 127, jj = tid >> 7;
  for(int i=tid;i<16*NN;i+=512)
    ts[i] = tt[((size_t)b*64 + jt*16)*NN + i];
  __syncthreads();
  float a0 = 0.f, a1 = 0.f, a2 = 0.f, a3 = 0.f;
  for(int ci=0;ci<NN;ci++){
    const float* wc = wT + (size_t)(ci*4)*NN + o;
    const float* tc2 = ts + (jj*4)*NN + ci;
    a0 = fmaf(tc2[0*NN], wc[0*NN], a0);
    a1 = fmaf(tc2[1*NN], wc[1*NN], a1);
    a2 = fmaf(tc2[2*NN], wc[2*NN], a2);
    a3 = fmaf(tc2[3*NN], wc[3*NN], a3);
  }
  int j = jt*4 + jj;
  t2[((size_t)b*NN + o)*16 + j] = (a0 + a1) + (a2 + a3) + bias[o];
}

// ---------------- K_h1: stage-1 conv + fast GELU -> h1g bf16 (full batch) ----------------
__global__ __launch_bounds__(256) void k_h1(const float* __restrict__ a0,
    const float* __restrict__ y64, const float* __restrict__ M64,
    const float* __restrict__ y16, const float* __restrict__ M16,
    const float* __restrict__ w0, const float* __restrict__ b0,
    const float* __restrict__ w1, const float* __restrict__ b1,
    bf16* __restrict__ h1g){
  constexpr int AY = 10, AX = 36;
  __shared__ alignas(16) float as[3][AY][AX];
  int tid = threadIdx.x;
  int l0 = blockIdx.x*8, n0 = blockIdx.y*32, b = blockIdx.z;
  float* asf = &as[0][0][0];
  for(int i=tid;i<3*AY*AX;i+=256){
    int ch = i/(AY*AX), rem = i%(AY*AX), yy = rem/AX, xx = rem%AX;
    int gl = l0 + yy - 1, gn = n0 + xx - 1;
    float v = 0.f;
    if(xx < 34 && gl >= 0 && gl < LL && gn >= 0 && gn < NN){
      if(ch == 0)      v = a0[((size_t)b*LL + gl)*NN + gn];
      else if(ch == 1) v = spline_pt(y64, M64, 64, gl, b, gn);
      else             v = spline_pt(y16, M16, 16, gl, b, gn);
    }
    asf[i] = v;
  }
  int c = tid & 31, qg = tid >> 5;
  float wr[3][3][3];
  #pragma unroll
  for(int ci=0;ci<3;ci++)
    #pragma unroll
    for(int dy=0;dy<3;dy++)
      #pragma unroll
      for(int dx=0;dx<3;dx++){
        float wv = 0.5f*w1[((c*3+ci)*3+dy)*3+dx];
        if(dy==1 && dx==1) wv += 0.5f*w0[c*3+ci];
        wr[ci][dy][dx] = wv;
      }
  float br = 0.5f*(b0[c] + b1[c]);
  __syncthreads();
  for(int q=qg; q<64; q+=8){
    int yy = q >> 3, x0q = (q & 7)*4;
    float win[3][3][6];
    #pragma unroll
    for(int ci=0;ci<3;ci++)
      #pragma unroll
      for(int dy=0;dy<3;dy++){
        float4 r4 = *(const float4*)&as[ci][yy+dy][x0q];
        float2 r2 = *(const float2*)&as[ci][yy+dy][x0q+4];
        win[ci][dy][0]=r4.x; win[ci][dy][1]=r4.y; win[ci][dy][2]=r4.z;
        win[ci][dy][3]=r4.w; win[ci][dy][4]=r2.x; win[ci][dy][5]=r2.y;
      }
    #pragma unroll
    for(int p=0;p<4;p++){
      float s = br;
      #pragma unroll
      for(int ci=0;ci<3;ci++)
        #pragma unroll
        for(int dy=0;dy<3;dy++)
          #pragma unroll
          for(int dx=0;dx<3;dx++)
            s = fmaf(wr[ci][dy][dx], win[ci][dy][p+dx], s);
      float val = gelu_fast(s);
      h1g[(((size_t)b*LL + l0 + yy)*NN + n0 + x0q + p)*DMC + c] = __float2bfloat16(val);
    }
  }
}

// ---------------- K_h2: stage-2 conv + residual, in-place into a0 (full batch) ----------------
__device__ __forceinline__ float2 bf2f2(unsigned u){
  float2 r;
  r.x = __uint_as_float(u << 16);
  r.y = __uint_as_float(u & 0xffff0000u);
  return r;
}

__global__ __launch_bounds__(256) void k_h2(const bf16* __restrict__ h1g,
    const float* __restrict__ vwsT, const float* __restrict__ vb0, const float* __restrict__ vb1,
    float* __restrict__ a0){
  __shared__ unsigned h1s[10][34][17];
  int tid = threadIdx.x;
  int l0 = blockIdx.x*8, n0 = blockIdx.y*32, b = blockIdx.z;
  const unsigned* hg = (const unsigned*)h1g;
  for(int i=tid;i<340*16;i+=256){
    int px = i >> 4, cp = i & 15;
    int yy = px/34, xx = px - yy*34;
    int gl = l0 + yy - 1, gn = n0 + xx - 1;
    unsigned u = 0;
    if(gl >= 0 && gl < LL && gn >= 0 && gn < NN)
      u = hg[(((size_t)b*LL + gl)*NN + gn)*16 + cp];
    h1s[yy][xx][cp] = u;
  }
  __syncthreads();
  int oy = tid >> 5, ox = tid & 31;
  float acc = 0.f;
  #pragma unroll
  for(int dy=0;dy<3;dy++)
    #pragma unroll
    for(int dx=0;dx<3;dx++){
      const unsigned* hp = &h1s[oy+dy][ox+dx][0];
      const float4* wt = (const float4*)(vwsT + (dy*3+dx)*DMC);
      #pragma unroll
      for(int cg=0;cg<8;cg++){
        unsigned u0 = hp[cg*2], u1 = hp[cg*2+1];
        float2 f0 = bf2f2(u0), f1 = bf2f2(u1);
        float4 wv = wt[cg];
        acc = fmaf(f0.x, wv.x, acc);
        acc = fmaf(f0.y, wv.y, acc);
        acc = fmaf(f1.x, wv.z, acc);
        acc = fmaf(f1.y, wv.w, acc);
      }
    }
  size_t idx = ((size_t)b*LL + l0 + oy)*NN + n0 + ox;
  a0[idx] = acc + vb0[0] + vb1[0] + a0[idx];
}

// ---------------- K15: GEMM2 via bf16 MFMA 16x16x32, 64x64 tile + de-normalize ----------------
// A[m=(b,n)][k=l] = a0[b][l][n], B[n'=p][k=l] = ldw[p][l]
__global__ __launch_bounds__(256) void k_gemm2(const float* __restrict__ a0, const float* __restrict__ ldw,
    const float* __restrict__ ldb, const float* __restrict__ sp, const float* __restrict__ s2p,
    float* __restrict__ out){
  __shared__ unsigned Asu[64*20];
  __shared__ unsigned Bsu[64*20];
  int tid = threadIdx.x;
  int row0 = blockIdx.x*64, p0 = blockIdx.y*64;
  int b = row0 >> 7, n0 = row0 & 127;
  int lane = tid & 63, wv = tid >> 6;
  frag_cd acc[4] = {};
  int an = tid & 63, akq = (tid >> 6)*8;
  int btk = tid & 15, blc = tid >> 4;
  unsigned ra[4], rbq[4];
  #pragma unroll
  for(int u=0;u<4;u++){
    float v0 = a0[((size_t)b*LL + akq + 2*u)*NN + n0 + an];
    float v1 = a0[((size_t)b*LL + akq + 2*u + 1)*NN + n0 + an];
    ra[u] = pbf2(v0, v1);
    const float* lp = ldw + (size_t)(p0 + blc + 16*u)*LL + 2*btk;
    rbq[u] = pbf2(lp[0], lp[1]);
  }
  int fr = wv*16 + (lane & 15);
  int fq = (lane >> 4)*4;
  for(int k0=0;k0<LL;k0+=32){
    *(uint4*)&Asu[an*20 + (akq>>1)] = make_uint4(ra[0], ra[1], ra[2], ra[3]);
    #pragma unroll
    for(int p=0;p<4;p++) Bsu[(blc + 16*p)*20 + btk] = rbq[p];
    __syncthreads();
    if(k0 + 32 < LL){
      #pragma unroll
      for(int u=0;u<4;u++){
        float v0 = a0[((size_t)b*LL + k0 + 32 + akq + 2*u)*NN + n0 + an];
        float v1 = a0[((size_t)b*LL + k0 + 32 + akq + 2*u + 1)*NN + n0 + an];
        ra[u] = pbf2(v0, v1);
        const float* lp = ldw + (size_t)(p0 + blc + 16*u)*LL + k0 + 32 + 2*btk;
        rbq[u] = pbf2(lp[0], lp[1]);
      }
    }
    frag_ab af = *(const frag_ab*)&Asu[fr*20 + fq];
    #pragma unroll
    for(int nt=0;nt<4;nt++){
      frag_ab bf = *(const frag_ab*)&Bsu[(nt*16 + (lane & 15))*20 + fq];
      acc[nt] = __builtin_amdgcn_mfma_f32_16x16x32_bf16(af, bf, acc[nt], 0, 0, 0);
    }
    __syncthreads();
  }
  int col = lane & 15, quad = lane >> 4;
  // de-norm constants for the 4 rows this lane owns
  float mu_r[4], sd_r[4];
  #pragma unroll
  for(int r=0;r<4;r++){
    int row = row0 + wv*16 + quad*4 + r;
    float ssum = 0.f, s2sum = 0.f;
    #pragma unroll
    for(int tq=0;tq<4;tq++){ ssum += sp[tq*2048 + row]; s2sum += s2p[tq*2048 + row]; }
    float mu = ssum*(1.f/512.f);
    float var = fmaxf(s2sum*(1.f/512.f) - mu*mu, 0.f);
    mu_r[r] = mu; sd_r[r] = sqrtf(var + EPSF);
  }
  #pragma unroll
  for(int nt=0;nt<4;nt++){
    int p = p0 + nt*16 + col;
    float lb = ldb[p];
    float4 st;
    st.x = (acc[nt][0] + lb)*sd_r[0] + mu_r[0];
    st.y = (acc[nt][1] + lb)*sd_r[1] + mu_r[1];
    st.z = (acc[nt][2] + lb)*sd_r[2] + mu_r[2];
    st.w = (acc[nt][3] + lb)*sd_r[3] + mu_r[3];
    *(float4*)&out[((size_t)b*PREDN + p)*NN + n0 + wv*16 + quad*4] = st;
  }
}

extern "C" void kernel_launch(void* const* d_in, const int* in_sizes, int n_in,
                              void* d_out, int out_size, void* d_ws, size_t ws_size,
                              hipStream_t stream){
  (void)in_sizes; (void)n_in; (void)out_size; (void)ws_size;
  const float* batch_x = (const float*)d_in[0];
  const float* le_w  = (const float*)d_in[4];
  const float* le_b  = (const float*)d_in[5];
  const float* c1_w  = (const float*)d_in[6];
  const float* c1_b  = (const float*)d_in[7];
  const float* bn1_g = (const float*)d_in[8];
  const float* bn1_b = (const float*)d_in[9];
  const float* c2_w  = (const float*)d_in[10];
  const float* c2_b  = (const float*)d_in[11];
  const float* bn2_g = (const float*)d_in[12];
  const float* bn2_b = (const float*)d_in[13];
  const float* i1_w0 = (const float*)d_in[14];
  const float* i1_b0 = (const float*)d_in[15];
  const float* i1_w1 = (const float*)d_in[16];
  const float* i1_b1 = (const float*)d_in[17];
  const float* i2_w0 = (const float*)d_in[18];
  const float* i2_b0 = (const float*)d_in[19];
  const float* i2_w1 = (const float*)d_in[20];
  const float* i2_b1 = (const float*)d_in[21];
  const float* ld_w  = (const float*)d_in[22];
  const float* ld_b  = (const float*)d_in[23];
  float* out = (float*)d_out;

  float* ws   = (float*)d_ws;
  float* sp   = ws;                        // 8192
  float* s2p  = sp + 8192;                 // 8192
  float* vwsT = s2p + 8192;                // 288 (+pad)
  float* wT1  = vwsT + 320;                // 196,608
  float* wT2  = wT1 + 196608;              // 65,536
  float* x    = wT2 + 65536;               // 1,572,864
  float* a0   = x + (size_t)BB*NN*LL;      // 1,572,864
  float* t1   = a0 + (size_t)BB*LL*NN;     // 131,072
  float* t1t  = t1 + (size_t)BB*NN*64;     // 131,072
  float* sc1  = t1t + (size_t)BB*64*NN;    // 128
  float* sh1  = sc1 + NN;                  // 128
  float* Msp1 = sh1 + NN;                  // 131,072
  float* t2   = Msp1 + (size_t)BB*64*NN;   // 32,768
  float* t2t  = t2 + (size_t)BB*NN*16;     // 32,768
  float* sc2  = t2t + (size_t)BB*16*NN;    // 128
  float* sh2  = sc2 + NN;                  // 128
  float* Msp2 = sh2 + NN;                  // 32,768
  bf16*  h1g  = (bf16*)(Msp2 + (size_t)BB*16*NN);  // full batch: 16*768*128*32 bf16 = 100.7 MB

  k_pre<<<321, 128, 0, stream>>>(batch_x, i2_w0, i2_w1, c1_w, c2_w, sp, s2p, vwsT, wT1, wT2);
  k_gemm1<<<dim3(32,12), 256, 0, stream>>>(batch_x, le_w, le_b, sp, s2p, x, a0);
  k_conv1<<<dim3(16,BB), 512, 0, stream>>>(x, wT1, c1_b, t1);
  k_bnstats<<<NN, 256, 0, stream>>>(t1, bn1_g, bn1_b, BB, 64, sc1, sh1);
  k_bnelu_t<<<dim3(64,BB), NN, 0, stream>>>(t1, sc1, sh1, 64, t1t);
  k_spline_solve<64><<<BB, NN, 0, stream>>>(t1t, Msp1);
  k_conv2<<<dim3(4,BB), 512, 0, stream>>>(t1t, wT2, c2_b, t2);
  k_bnstats<<<NN, 256, 0, stream>>>(t2, bn2_g, bn2_b, BB, 16, sc2, sh2);
  k_bnelu_t<<<dim3(16,BB), NN, 0, stream>>>(t2, sc2, sh2, 16, t2t);
  k_spline_solve<16><<<BB, NN, 0, stream>>>(t2t, Msp2);
  k_h1<<<dim3(96,4,BB), 256, 0, stream>>>(a0, t1t, Msp1, t2t, Msp2,
                                          i1_w0, i1_b0, i1_w1, i1_b1, h1g);
  k_h2<<<dim3(96,4,BB), 256, 0, stream>>>(h1g, vwsT, i2_b0, i2_b1, a0);
  k_gemm2<<<dim3(32,4), 256, 0, stream>>>(a0, ld_w, ld_b, sp, s2p, out);
}